// Round 4
// baseline (278.894 us; speedup 1.0000x reference)
//
#include <hip/hip_runtime.h>

#define N 9216
#define CIN 256
#define DQ 32
#define NT 144                      // N / 64
#define LOG2E 1.44269504088896340736f

typedef short short8 __attribute__((ext_vector_type(8)));   // 8 bf16 in 4 VGPRs
typedef float floatx4 __attribute__((ext_vector_type(4)));
typedef unsigned short ushort_t;

__device__ __forceinline__ ushort_t f2bf(float f) {
  union { float f; unsigned u; } a; a.f = f;
  unsigned u = a.u;
  u += 0x7fffu + ((u >> 16) & 1u);   // round-to-nearest-even
  return (ushort_t)(u >> 16);
}
__device__ __forceinline__ float bf2f(ushort_t h) {
  union { unsigned u; float f; } a; a.u = ((unsigned)h) << 16;
  return a.f;
}

// ---------------------------------------------------------------------------
// Kernel 1: q/k/v projections.  grid (144 n-tiles, 5 o-chunks), 256 threads.
// ---------------------------------------------------------------------------
__global__ __launch_bounds__(256) void qkv_kernel(
    const float* __restrict__ x,
    const float* __restrict__ Wq, const float* __restrict__ bq,
    const float* __restrict__ Wk, const float* __restrict__ bk,
    const float* __restrict__ Wv, const float* __restrict__ bv,
    ushort_t* __restrict__ qT, ushort_t* __restrict__ kT,
    ushort_t* __restrict__ vG)
{
  __shared__ float xs[64][68];          // stride 68: 16B-aligned rows, ~2-way banks
  const int t = threadIdx.x;
  const int n0 = blockIdx.x * 64;
  const int oc = blockIdx.y;            // 0..4 ; chunk0 = Wq(32)+Wk(32), 1..4 = Wv
  const int i = t >> 4, j = t & 15;
  const int o0 = oc * 64 + i * 4;

  const float* Wrow[4];
  float bias[4];
#pragma unroll
  for (int r = 0; r < 4; ++r) {
    const int o = o0 + r;
    if (oc == 0) {
      if (o < 32) { Wrow[r] = Wq + o * CIN;        bias[r] = bq[o]; }
      else        { Wrow[r] = Wk + (o - 32) * CIN; bias[r] = bk[o - 32]; }
    } else        { Wrow[r] = Wv + (o - 64) * CIN; bias[r] = bv[o - 64]; }
  }

  float acc[4][4] = {};
  for (int cc = 0; cc < 4; ++cc) {
    {
      const int row = t >> 2, cq = t & 3;
      const float* src = x + (size_t)(cc * 64 + row) * N + n0 + cq * 16;
      float4 a0 = *(const float4*)(src + 0);
      float4 a1 = *(const float4*)(src + 4);
      float4 a2 = *(const float4*)(src + 8);
      float4 a3 = *(const float4*)(src + 12);
      float* dst = &xs[row][cq * 16];
      *(float4*)(dst + 0) = a0; *(float4*)(dst + 4)  = a1;
      *(float4*)(dst + 8) = a2; *(float4*)(dst + 12) = a3;
    }
    __syncthreads();
#pragma unroll 2
    for (int k4 = 0; k4 < 16; ++k4) {
      float4 wv4[4];
#pragma unroll
      for (int r = 0; r < 4; ++r)
        wv4[r] = *(const float4*)(Wrow[r] + cc * 64 + k4 * 4);
#pragma unroll
      for (int kk = 0; kk < 4; ++kk) {
        float4 xv = *(const float4*)&xs[k4 * 4 + kk][j * 4];
#pragma unroll
        for (int r = 0; r < 4; ++r) {
          const float wval = ((const float*)&wv4[r])[kk];
          acc[r][0] += wval * xv.x;
          acc[r][1] += wval * xv.y;
          acc[r][2] += wval * xv.z;
          acc[r][3] += wval * xv.w;
        }
      }
    }
    __syncthreads();
  }

#pragma unroll
  for (int r = 0; r < 4; ++r) {
    const int o = o0 + r;
#pragma unroll
    for (int c = 0; c < 4; ++c) {
      const int n = n0 + j * 4 + c;
      const float val = acc[r][c] + bias[r];
      if (oc == 0) {
        if (o < 32) qT[(size_t)n * DQ + o]        = f2bf(val * LOG2E);
        else        kT[(size_t)n * DQ + (o - 32)] = f2bf(val);
      } else        vG[(size_t)(o - 64) * N + n]  = f2bf(val);
    }
  }
}

// ---------------------------------------------------------------------------
// Kernel 2: flash attention, 64-m tiles.  grid (144 n-tiles, nsl m-slices),
// 256 threads = 4 waves.  R3 showed latency-bound at 3 blocks/CU (68 VGPR +
// 64 AGPR = 132 regs unified file -> 3 waves/SIMD) with a barrier every 18
// MFMAs.  This version: 64 m per iteration -> barriers halved (18/block),
// 12 global loads in flight per iter, 36 MFMAs per barrier (AITER-like).
// __launch_bounds__(256,3) pins 3 waves/SIMD (reg cap ~170, est use ~150).
// ---------------------------------------------------------------------------
__global__ __launch_bounds__(256, 3) void attn_kernel(
    const ushort_t* __restrict__ qT, const ushort_t* __restrict__ kT,
    const ushort_t* __restrict__ vG,
    ushort_t* __restrict__ Opart, float* __restrict__ lpart,
    int mIters)
{
  __shared__ ushort_t Pb[2][64][68];    // double-buffered P tile (64n x 64m)

  const int t = threadIdx.x;
  const int w = t >> 6;
  const int lane = t & 63;
  const int quad = lane >> 4;
  const int l15 = lane & 15;
  const int nt = blockIdx.x;
  const int s  = blockIdx.y;
  const int n0 = nt * 64;
  const int mbase = s * mIters * 64;
  const int cw = w * 64;

  // Q A-fragment: invariant over the m-loop. lane holds A[m=l15][k=8*quad+j].
  short8 aq = *(const short8*)(qT + (size_t)(n0 + 16 * w + l15) * DQ + 8 * quad);

  floatx4 acc[4][4];
#pragma unroll
  for (int a2 = 0; a2 < 4; ++a2)
#pragma unroll
    for (int b2 = 0; b2 < 4; ++b2)
      acc[a2][b2] = (floatx4){0.f, 0.f, 0.f, 0.f};
  float lsum[4] = {0.f, 0.f, 0.f, 0.f};
  const floatx4 z4 = {0.f, 0.f, 0.f, 0.f};

  for (int it = 0; it < mIters; ++it) {
    const int m0 = mbase + it * 64;

    // K B-frags for S (4 x 16m): lane holds B[k=8*quad+j][n=l15] from kT rows.
    const ushort_t* kr = kT + (size_t)(m0 + l15) * DQ + 8 * quad;
    short8 kb0 = *(const short8*)(kr);
    short8 kb1 = *(const short8*)(kr + 16 * DQ);
    short8 kb2 = *(const short8*)(kr + 32 * DQ);
    short8 kb3 = *(const short8*)(kr + 48 * DQ);

    // V A-frags from global: A[m=c(l15)][k=m(8*quad+j)], 16B/lane, both halves.
    const ushort_t* vb = vG + (size_t)m0 + 8 * quad;
    short8 av0 = *(const short8*)(vb + (size_t)(cw +  0 + l15) * N);
    short8 av1 = *(const short8*)(vb + (size_t)(cw + 16 + l15) * N);
    short8 av2 = *(const short8*)(vb + (size_t)(cw + 32 + l15) * N);
    short8 av3 = *(const short8*)(vb + (size_t)(cw + 48 + l15) * N);
    short8 av4 = *(const short8*)(vb + (size_t)(cw +  0 + l15) * N + 32);
    short8 av5 = *(const short8*)(vb + (size_t)(cw + 16 + l15) * N + 32);
    short8 av6 = *(const short8*)(vb + (size_t)(cw + 32 + l15) * N + 32);
    short8 av7 = *(const short8*)(vb + (size_t)(cw + 48 + l15) * N + 32);

    // S tiles (16n x 64m)
    floatx4 s0 = __builtin_amdgcn_mfma_f32_16x16x32_bf16(aq, kb0, z4, 0, 0, 0);
    floatx4 s1 = __builtin_amdgcn_mfma_f32_16x16x32_bf16(aq, kb1, z4, 0, 0, 0);
    floatx4 s2 = __builtin_amdgcn_mfma_f32_16x16x32_bf16(aq, kb2, z4, 0, 0, 0);
    floatx4 s3 = __builtin_amdgcn_mfma_f32_16x16x32_bf16(aq, kb3, z4, 0, 0, 0);

    // exp2 (q pre-scaled by log2e) + sumexp + P -> LDS.
    ushort_t* pb = &Pb[it & 1][0][0];
#pragma unroll
    for (int r = 0; r < 4; ++r) {
      float p0 = exp2f(s0[r]);
      float p1 = exp2f(s1[r]);
      float p2 = exp2f(s2[r]);
      float p3 = exp2f(s3[r]);
      lsum[r] += (p0 + p1) + (p2 + p3);
      ushort_t* pr = pb + (16 * w + 4 * quad + r) * 68 + l15;
      pr[0]  = f2bf(p0);
      pr[16] = f2bf(p1);
      pr[32] = f2bf(p2);
      pr[48] = f2bf(p3);
    }
    __syncthreads();   // single barrier/iter: double buffer covers WAR hazard

    // O^T += V * P^T : B-frag lane holds P[n=b2*16+l15][m=8*quad+j (+32)].
#pragma unroll
    for (int b2 = 0; b2 < 4; ++b2) {
      const ushort_t* pr = pb + (b2 * 16 + l15) * 68 + 8 * quad;
      union { uint2 u2[2]; short8 v; } u0, u1;
      u0.u2[0] = *(const uint2*)(pr);
      u0.u2[1] = *(const uint2*)(pr + 4);
      u1.u2[0] = *(const uint2*)(pr + 32);
      u1.u2[1] = *(const uint2*)(pr + 36);
      const short8 pf0 = u0.v;
      const short8 pf1 = u1.v;
      acc[0][b2] = __builtin_amdgcn_mfma_f32_16x16x32_bf16(av0, pf0, acc[0][b2], 0, 0, 0);
      acc[1][b2] = __builtin_amdgcn_mfma_f32_16x16x32_bf16(av1, pf0, acc[1][b2], 0, 0, 0);
      acc[2][b2] = __builtin_amdgcn_mfma_f32_16x16x32_bf16(av2, pf0, acc[2][b2], 0, 0, 0);
      acc[3][b2] = __builtin_amdgcn_mfma_f32_16x16x32_bf16(av3, pf0, acc[3][b2], 0, 0, 0);
      acc[0][b2] = __builtin_amdgcn_mfma_f32_16x16x32_bf16(av4, pf1, acc[0][b2], 0, 0, 0);
      acc[1][b2] = __builtin_amdgcn_mfma_f32_16x16x32_bf16(av5, pf1, acc[1][b2], 0, 0, 0);
      acc[2][b2] = __builtin_amdgcn_mfma_f32_16x16x32_bf16(av6, pf1, acc[2][b2], 0, 0, 0);
      acc[3][b2] = __builtin_amdgcn_mfma_f32_16x16x32_bf16(av7, pf1, acc[3][b2], 0, 0, 0);
    }
  }

  // sumexp: reduce over the 16 lanes sharing a quad
#pragma unroll
  for (int r = 0; r < 4; ++r) {
    float v = lsum[r];
    v += __shfl_xor(v, 1);
    v += __shfl_xor(v, 2);
    v += __shfl_xor(v, 4);
    v += __shfl_xor(v, 8);
    lsum[r] = v;
  }
  if (l15 == 0) {
#pragma unroll
    for (int r = 0; r < 4; ++r)
      lpart[(size_t)s * N + n0 + 16 * w + 4 * quad + r] = lsum[r];
  }

  // store O^T partial, layout [s][nt][c:256][n:64]
  const size_t base = ((size_t)s * NT + nt) * 256;
#pragma unroll
  for (int a2 = 0; a2 < 4; ++a2)
#pragma unroll
    for (int b2 = 0; b2 < 4; ++b2)
#pragma unroll
      for (int r = 0; r < 4; ++r) {
        const int c  = cw + a2 * 16 + 4 * quad + r;
        const int nl = b2 * 16 + l15;
        Opart[(base + c) * 64 + nl] = f2bf(acc[a2][b2][r]);
      }
}

// ---------------------------------------------------------------------------
// Kernel 3: combine stage A.  grid (144 n-tiles, 8 c-groups) = 1152 blocks.
// ---------------------------------------------------------------------------
__global__ __launch_bounds__(256) void cco_partial(
    const ushort_t* __restrict__ Opart,
    float* __restrict__ pmax, float* __restrict__ psum, int nsl)
{
  const int nt = blockIdx.x, cy = blockIdx.y;
  const int t = threadIdx.x;
  const int n = t & 63, ci = t >> 6;
  float mx = -3.4e38f, sm = 0.f;
#pragma unroll
  for (int k = 0; k < 8; ++k) {
    const int c = cy * 32 + ci + 4 * k;
    float val = 0.f;
#pragma unroll 8
    for (int s2 = 0; s2 < nsl; ++s2)
      val += bf2f(Opart[(((size_t)s2 * NT + nt) * 256 + c) * 64 + n]);
    mx = fmaxf(mx, val);
    sm += val;
  }
  __shared__ float rmx[4][64], rsm[4][64];
  rmx[ci][n] = mx; rsm[ci][n] = sm;
  __syncthreads();
  if (t < 64) {
    const float m2 = fmaxf(fmaxf(rmx[0][t], rmx[1][t]), fmaxf(rmx[2][t], rmx[3][t]));
    const float s2 = rsm[0][t] + rsm[1][t] + rsm[2][t] + rsm[3][t];
    pmax[(size_t)cy * N + nt * 64 + t] = m2;
    psum[(size_t)cy * N + nt * 64 + t] = s2;
  }
}

// ---------------------------------------------------------------------------
// Kernel 4: gate (merged with old cco_final).  One block, 1024 threads.
// out_co[n] = (max + mean/256)/sumexp ; x_co = softmax(out_co / 16).
// ---------------------------------------------------------------------------
__global__ __launch_bounds__(1024) void gate_kernel(
    const float* __restrict__ pmax, const float* __restrict__ psum,
    const float* __restrict__ lpart, float* __restrict__ x_co, int nsl)
{
  const int t = threadIdx.x;
  float z[9];
#pragma unroll
  for (int i2 = 0; i2 < 9; ++i2) {
    const int n = t + 1024 * i2;
    float m = -3.4e38f, s = 0.f, l = 0.f;
#pragma unroll
    for (int g = 0; g < 8; ++g) {
      m = fmaxf(m, pmax[(size_t)g * N + n]);
      s += psum[(size_t)g * N + n];
    }
#pragma unroll 8
    for (int s3 = 0; s3 < nsl; ++s3) l += lpart[(size_t)s3 * N + n];
    z[i2] = ((m + s * (1.0f / 256.0f)) / l) * 0.0625f;
  }
  float mx = z[0];
#pragma unroll
  for (int i2 = 1; i2 < 9; ++i2) mx = fmaxf(mx, z[i2]);
  for (int off = 32; off > 0; off >>= 1) mx = fmaxf(mx, __shfl_xor(mx, off));
  __shared__ float redm[16], reds[16];
  const int wv = t >> 6, ln = t & 63;
  if (ln == 0) redm[wv] = mx;
  __syncthreads();
  mx = redm[0];
#pragma unroll
  for (int i2 = 1; i2 < 16; ++i2) mx = fmaxf(mx, redm[i2]);

  float e[9]; float sm = 0.f;
#pragma unroll
  for (int i2 = 0; i2 < 9; ++i2) { e[i2] = exp2f((z[i2] - mx) * LOG2E); sm += e[i2]; }
  for (int off = 32; off > 0; off >>= 1) sm += __shfl_xor(sm, off);
  if (ln == 0) reds[wv] = sm;
  __syncthreads();
  sm = 0.f;
#pragma unroll
  for (int i2 = 0; i2 < 16; ++i2) sm += reds[i2];
  const float inv = 1.0f / sm;
#pragma unroll
  for (int i2 = 0; i2 < 9; ++i2) x_co[t + 1024 * i2] = e[i2] * inv;
}

// ---------------------------------------------------------------------------
// Kernel 5: out = x + (1+gamma)*(x_co[n]*(W6@x)[o][n] + b6[o])
// ---------------------------------------------------------------------------
__global__ __launch_bounds__(256) void final_kernel(
    const float* __restrict__ x, const float* __restrict__ W6,
    const float* __restrict__ b6, const float* __restrict__ gamma,
    const float* __restrict__ x_co, float* __restrict__ out)
{
  __shared__ float xs[64][68];
  const int t = threadIdx.x;
  const int n0 = blockIdx.x * 64;
  const int i = t >> 4, j = t & 15;
  const int o0 = blockIdx.y * 64 + i * 4;

  float acc[4][4] = {};
  for (int cc = 0; cc < 4; ++cc) {
    {
      const int row = t >> 2, cq = t & 3;
      const float* src = x + (size_t)(cc * 64 + row) * N + n0 + cq * 16;
      float4 a0 = *(const float4*)(src + 0);
      float4 a1 = *(const float4*)(src + 4);
      float4 a2 = *(const float4*)(src + 8);
      float4 a3 = *(const float4*)(src + 12);
      float* dst = &xs[row][cq * 16];
      *(float4*)(dst + 0) = a0; *(float4*)(dst + 4)  = a1;
      *(float4*)(dst + 8) = a2; *(float4*)(dst + 12) = a3;
    }
    __syncthreads();
#pragma unroll 2
    for (int k4 = 0; k4 < 16; ++k4) {
      float4 wv4[4];
#pragma unroll
      for (int r = 0; r < 4; ++r)
        wv4[r] = *(const float4*)(W6 + (size_t)(o0 + r) * CIN + cc * 64 + k4 * 4);
#pragma unroll
      for (int kk = 0; kk < 4; ++kk) {
        float4 xv = *(const float4*)&xs[k4 * 4 + kk][j * 4];
#pragma unroll
        for (int r = 0; r < 4; ++r) {
          const float wval = ((const float*)&wv4[r])[kk];
          acc[r][0] += wval * xv.x;
          acc[r][1] += wval * xv.y;
          acc[r][2] += wval * xv.z;
          acc[r][3] += wval * xv.w;
        }
      }
    }
    __syncthreads();
  }

  const float g1 = 1.0f + gamma[0];
  const float4 xc = *(const float4*)(x_co + n0 + j * 4);
#pragma unroll
  for (int r = 0; r < 4; ++r) {
    const int o = o0 + r;
    const float bv6 = b6[o];
    const float4 xrow = *(const float4*)(x + (size_t)o * N + n0 + j * 4);
    float4 res;
    res.x = xrow.x + g1 * (xc.x * acc[r][0] + bv6);
    res.y = xrow.y + g1 * (xc.y * acc[r][1] + bv6);
    res.z = xrow.z + g1 * (xc.z * acc[r][2] + bv6);
    res.w = xrow.w + g1 * (xc.w * acc[r][3] + bv6);
    *(float4*)(out + (size_t)o * N + n0 + j * 4) = res;
  }
}

// ---------------------------------------------------------------------------
extern "C" void kernel_launch(void* const* d_in, const int* in_sizes, int n_in,
                              void* d_out, int out_size, void* d_ws, size_t ws_size,
                              hipStream_t stream)
{
  const float* x     = (const float*)d_in[0];
  const float* Wq    = (const float*)d_in[1];
  const float* bq    = (const float*)d_in[2];
  const float* Wk    = (const float*)d_in[3];
  const float* bk    = (const float*)d_in[4];
  const float* Wv    = (const float*)d_in[5];
  const float* bv    = (const float*)d_in[6];
  const float* W6    = (const float*)d_in[7];
  const float* b6    = (const float*)d_in[8];
  const float* gamma = (const float*)d_in[9];
  float* out = (float*)d_out;

  // nsl = 8 -> 1152 attn blocks.  Fallback nsl = 4 if ws too small.
  const size_t fixed = (size_t)N * DQ * 2 * 2        // qT,kT
                     + (size_t)CIN * N * 2            // vG
                     + (size_t)N * 4                  // x_co
                     + (size_t)8 * N * 4 * 2;         // pmax, psum
  int nsl = 8;
  size_t need8 = fixed + (size_t)8 * NT * 256 * 64 * 2 + (size_t)8 * N * 4;
  if (ws_size < need8) nsl = 4;
  const int mIters = (N / nsl) / 64;

  char* ws = (char*)d_ws;
  const size_t OFF_QT = 0;
  const size_t OFF_KT = OFF_QT + (size_t)N * DQ * 2;
  const size_t OFF_V  = OFF_KT + (size_t)N * DQ * 2;
  const size_t OFF_OP = OFF_V  + (size_t)CIN * N * 2;
  const size_t OFF_LP = OFF_OP + (size_t)nsl * NT * 256 * 64 * 2;
  const size_t OFF_PM = OFF_LP + (size_t)nsl * N * 4;
  const size_t OFF_PS = OFF_PM + (size_t)8 * N * 4;
  const size_t OFF_XC = OFF_PS + (size_t)8 * N * 4;

  ushort_t* qT     = (ushort_t*)(ws + OFF_QT);
  ushort_t* kT     = (ushort_t*)(ws + OFF_KT);
  ushort_t* vG     = (ushort_t*)(ws + OFF_V);
  ushort_t* Opart  = (ushort_t*)(ws + OFF_OP);
  float*    lpart  = (float*)(ws + OFF_LP);
  float*    pmax   = (float*)(ws + OFF_PM);
  float*    psum   = (float*)(ws + OFF_PS);
  float*    x_co   = (float*)(ws + OFF_XC);

  qkv_kernel<<<dim3(NT, 5), 256, 0, stream>>>(x, Wq, bq, Wk, bk, Wv, bv, qT, kT, vG);
  attn_kernel<<<dim3(NT, nsl), 256, 0, stream>>>(qT, kT, vG, Opart, lpart, mIters);
  cco_partial<<<dim3(NT, 8), 256, 0, stream>>>(Opart, pmax, psum, nsl);
  gate_kernel<<<1, 1024, 0, stream>>>(pmax, psum, lpart, x_co, nsl);
  final_kernel<<<dim3(NT, 4), 256, 0, stream>>>(x, W6, b6, gamma, x_co, out);
}

// Round 5
// 262.006 us; speedup vs baseline: 1.0645x; 1.0645x over previous
//
#include <hip/hip_runtime.h>

#define N 9216
#define CIN 256
#define DQ 32
#define NT 144                      // N / 64
#define LOG2E 1.44269504088896340736f

typedef short short8 __attribute__((ext_vector_type(8)));   // 8 bf16 in 4 VGPRs
typedef float floatx4 __attribute__((ext_vector_type(4)));
typedef unsigned short ushort_t;

__device__ __forceinline__ ushort_t f2bf(float f) {
  union { float f; unsigned u; } a; a.f = f;
  unsigned u = a.u;
  u += 0x7fffu + ((u >> 16) & 1u);   // round-to-nearest-even
  return (ushort_t)(u >> 16);
}
// cheap round-to-nearest (no RNE tie handling): 2 VALU ops instead of 5.
__device__ __forceinline__ ushort_t f2bf_fast(float f) {
  union { float f; unsigned u; } a; a.f = f;
  return (ushort_t)((a.u + 0x8000u) >> 16);
}
__device__ __forceinline__ float bf2f(ushort_t h) {
  union { unsigned u; float f; } a; a.u = ((unsigned)h) << 16;
  return a.f;
}

// ---------------------------------------------------------------------------
// Kernel 1: q/k/v projections.  grid (144 n-tiles, 5 o-chunks), 256 threads.
// ---------------------------------------------------------------------------
__global__ __launch_bounds__(256) void qkv_kernel(
    const float* __restrict__ x,
    const float* __restrict__ Wq, const float* __restrict__ bq,
    const float* __restrict__ Wk, const float* __restrict__ bk,
    const float* __restrict__ Wv, const float* __restrict__ bv,
    ushort_t* __restrict__ qT, ushort_t* __restrict__ kT,
    ushort_t* __restrict__ vG)
{
  __shared__ float xs[64][68];          // stride 68: 16B-aligned rows, ~2-way banks
  const int t = threadIdx.x;
  const int n0 = blockIdx.x * 64;
  const int oc = blockIdx.y;            // 0..4 ; chunk0 = Wq(32)+Wk(32), 1..4 = Wv
  const int i = t >> 4, j = t & 15;
  const int o0 = oc * 64 + i * 4;

  const float* Wrow[4];
  float bias[4];
#pragma unroll
  for (int r = 0; r < 4; ++r) {
    const int o = o0 + r;
    if (oc == 0) {
      if (o < 32) { Wrow[r] = Wq + o * CIN;        bias[r] = bq[o]; }
      else        { Wrow[r] = Wk + (o - 32) * CIN; bias[r] = bk[o - 32]; }
    } else        { Wrow[r] = Wv + (o - 64) * CIN; bias[r] = bv[o - 64]; }
  }

  float acc[4][4] = {};
  for (int cc = 0; cc < 4; ++cc) {
    {
      const int row = t >> 2, cq = t & 3;
      const float* src = x + (size_t)(cc * 64 + row) * N + n0 + cq * 16;
      float4 a0 = *(const float4*)(src + 0);
      float4 a1 = *(const float4*)(src + 4);
      float4 a2 = *(const float4*)(src + 8);
      float4 a3 = *(const float4*)(src + 12);
      float* dst = &xs[row][cq * 16];
      *(float4*)(dst + 0) = a0; *(float4*)(dst + 4)  = a1;
      *(float4*)(dst + 8) = a2; *(float4*)(dst + 12) = a3;
    }
    __syncthreads();
#pragma unroll 2
    for (int k4 = 0; k4 < 16; ++k4) {
      float4 wv4[4];
#pragma unroll
      for (int r = 0; r < 4; ++r)
        wv4[r] = *(const float4*)(Wrow[r] + cc * 64 + k4 * 4);
#pragma unroll
      for (int kk = 0; kk < 4; ++kk) {
        float4 xv = *(const float4*)&xs[k4 * 4 + kk][j * 4];
#pragma unroll
        for (int r = 0; r < 4; ++r) {
          const float wval = ((const float*)&wv4[r])[kk];
          acc[r][0] += wval * xv.x;
          acc[r][1] += wval * xv.y;
          acc[r][2] += wval * xv.z;
          acc[r][3] += wval * xv.w;
        }
      }
    }
    __syncthreads();
  }

#pragma unroll
  for (int r = 0; r < 4; ++r) {
    const int o = o0 + r;
#pragma unroll
    for (int c = 0; c < 4; ++c) {
      const int n = n0 + j * 4 + c;
      const float val = acc[r][c] + bias[r];
      if (oc == 0) {
        if (o < 32) qT[(size_t)n * DQ + o]        = f2bf(val * LOG2E);
        else        kT[(size_t)n * DQ + (o - 32)] = f2bf(val);
      } else        vG[(size_t)(o - 64) * N + n]  = f2bf(val);
    }
  }
}

// ---------------------------------------------------------------------------
// Kernel 2: flash attention, 32-m tiles (R3 structure).  grid (144, nsl),
// 256 threads = 4 waves.  R4 analysis: 3 waves/SIMD because 68 VGPR + 64 AGPR
// = 132 > 128 in the unified file -- 4 regs over the 4-waves/SIMD boundary.
// __launch_bounds__(256,4) caps at 128; f2bf_fast (2 ops) and post-S V loads
// cut VALU + live ranges to help the allocator land under the cap.
// ---------------------------------------------------------------------------
__global__ __launch_bounds__(256, 4) void attn_kernel(
    const ushort_t* __restrict__ qT, const ushort_t* __restrict__ kT,
    const ushort_t* __restrict__ vG,
    ushort_t* __restrict__ Opart, float* __restrict__ lpart,
    int sliceIters)
{
  __shared__ ushort_t Pb[2][64][36];    // double-buffered P tile (64n x 32m)

  const int t = threadIdx.x;
  const int w = t >> 6;
  const int lane = t & 63;
  const int quad = lane >> 4;
  const int l15 = lane & 15;
  const int nt = blockIdx.x;
  const int s  = blockIdx.y;
  const int n0 = nt * 64;
  const int mbase = s * sliceIters * 32;
  const int cw = w * 64;

  // Q A-fragment: invariant over the m-loop. lane holds A[m=l15][k=8*quad+j].
  short8 aq = *(const short8*)(qT + (size_t)(n0 + 16 * w + l15) * DQ + 8 * quad);

  floatx4 acc[4][4];
#pragma unroll
  for (int a2 = 0; a2 < 4; ++a2)
#pragma unroll
    for (int b2 = 0; b2 < 4; ++b2)
      acc[a2][b2] = (floatx4){0.f, 0.f, 0.f, 0.f};
  float lsum[4] = {0.f, 0.f, 0.f, 0.f};
  const floatx4 z4 = {0.f, 0.f, 0.f, 0.f};

  for (int it = 0; it < sliceIters; ++it) {
    const int m0 = mbase + it * 32;

    // S tile (16n x 32m): B-frag lane holds B[k=8*quad+j][n=l15] from kT rows.
    short8 kb0 = *(const short8*)(kT + (size_t)(m0 + l15) * DQ + 8 * quad);
    short8 kb1 = *(const short8*)(kT + (size_t)(m0 + 16 + l15) * DQ + 8 * quad);
    floatx4 s0 = __builtin_amdgcn_mfma_f32_16x16x32_bf16(aq, kb0, z4, 0, 0, 0);
    floatx4 s1 = __builtin_amdgcn_mfma_f32_16x16x32_bf16(aq, kb1, z4, 0, 0, 0);

    // V A-frags from global: A[m=c(l15)][k=m(8*quad+j)], 16B/lane.
    // Issued after S so their latency overlaps exp2/pack/barrier.
    const ushort_t* vb = vG + (size_t)m0 + 8 * quad;
    short8 av0 = *(const short8*)(vb + (size_t)(cw +  0 + l15) * N);
    short8 av1 = *(const short8*)(vb + (size_t)(cw + 16 + l15) * N);
    short8 av2 = *(const short8*)(vb + (size_t)(cw + 32 + l15) * N);
    short8 av3 = *(const short8*)(vb + (size_t)(cw + 48 + l15) * N);

    // exp2 (q pre-scaled by log2e) + sumexp + P -> LDS.
    ushort_t* pb = &Pb[it & 1][0][0];
#pragma unroll
    for (int r = 0; r < 4; ++r) {
      float p0 = exp2f(s0[r]);
      float p1 = exp2f(s1[r]);
      lsum[r] += p0 + p1;
      const int row = 16 * w + 4 * quad + r;
      pb[row * 36 + l15]      = f2bf_fast(p0);
      pb[row * 36 + 16 + l15] = f2bf_fast(p1);
    }
    __syncthreads();   // single barrier/iter: double buffer covers WAR hazard

    // O^T += V * P^T : B-frag lane holds P[n=b2*16+l15][m=8*quad+j].
#pragma unroll
    for (int b2 = 0; b2 < 4; ++b2) {
      const ushort_t* pr = pb + (b2 * 16 + l15) * 36 + 8 * quad;
      union { uint2 u2[2]; short8 v; } u;
      u.u2[0] = *(const uint2*)(pr);
      u.u2[1] = *(const uint2*)(pr + 4);
      const short8 pf = u.v;
      acc[0][b2] = __builtin_amdgcn_mfma_f32_16x16x32_bf16(av0, pf, acc[0][b2], 0, 0, 0);
      acc[1][b2] = __builtin_amdgcn_mfma_f32_16x16x32_bf16(av1, pf, acc[1][b2], 0, 0, 0);
      acc[2][b2] = __builtin_amdgcn_mfma_f32_16x16x32_bf16(av2, pf, acc[2][b2], 0, 0, 0);
      acc[3][b2] = __builtin_amdgcn_mfma_f32_16x16x32_bf16(av3, pf, acc[3][b2], 0, 0, 0);
    }
  }

  // sumexp: reduce over the 16 lanes sharing a quad
#pragma unroll
  for (int r = 0; r < 4; ++r) {
    float v = lsum[r];
    v += __shfl_xor(v, 1);
    v += __shfl_xor(v, 2);
    v += __shfl_xor(v, 4);
    v += __shfl_xor(v, 8);
    lsum[r] = v;
  }
  if (l15 == 0) {
#pragma unroll
    for (int r = 0; r < 4; ++r)
      lpart[(size_t)s * N + n0 + 16 * w + 4 * quad + r] = lsum[r];
  }

  // store O^T partial, layout [s][nt][c:256][n:64]
  const size_t base = ((size_t)s * NT + nt) * 256;
#pragma unroll
  for (int a2 = 0; a2 < 4; ++a2)
#pragma unroll
    for (int b2 = 0; b2 < 4; ++b2)
#pragma unroll
      for (int r = 0; r < 4; ++r) {
        const int c  = cw + a2 * 16 + 4 * quad + r;
        const int nl = b2 * 16 + l15;
        Opart[(base + c) * 64 + nl] = f2bf(acc[a2][b2][r]);
      }
}

// ---------------------------------------------------------------------------
// Kernel 3a: combine stage A.  grid (144 n-tiles, 8 c-groups) = 1152 blocks.
// ---------------------------------------------------------------------------
__global__ __launch_bounds__(256) void cco_partial(
    const ushort_t* __restrict__ Opart,
    float* __restrict__ pmax, float* __restrict__ psum, int nsl)
{
  const int nt = blockIdx.x, cy = blockIdx.y;
  const int t = threadIdx.x;
  const int n = t & 63, ci = t >> 6;
  float mx = -3.4e38f, sm = 0.f;
#pragma unroll
  for (int k = 0; k < 8; ++k) {
    const int c = cy * 32 + ci + 4 * k;
    float val = 0.f;
#pragma unroll 8
    for (int s2 = 0; s2 < nsl; ++s2)
      val += bf2f(Opart[(((size_t)s2 * NT + nt) * 256 + c) * 64 + n]);
    mx = fmaxf(mx, val);
    sm += val;
  }
  __shared__ float rmx[4][64], rsm[4][64];
  rmx[ci][n] = mx; rsm[ci][n] = sm;
  __syncthreads();
  if (t < 64) {
    const float m2 = fmaxf(fmaxf(rmx[0][t], rmx[1][t]), fmaxf(rmx[2][t], rmx[3][t]));
    const float s2 = rsm[0][t] + rsm[1][t] + rsm[2][t] + rsm[3][t];
    pmax[(size_t)cy * N + nt * 64 + t] = m2;
    psum[(size_t)cy * N + nt * 64 + t] = s2;
  }
}

// ---------------------------------------------------------------------------
// Kernel 3b: combine stage B.  out_co[n] = (max + mean/256) / sumexp.
// 36 blocks x 256 threads, all loads coalesced.  (Separate from gate: the
// R4 merge into the 1-block gate cost ~25 us.)
// ---------------------------------------------------------------------------
__global__ __launch_bounds__(256) void cco_final(
    const float* __restrict__ pmax, const float* __restrict__ psum,
    const float* __restrict__ lpart, float* __restrict__ out_co, int nsl)
{
  const int n = blockIdx.x * 256 + threadIdx.x;
  float m = -3.4e38f, s = 0.f, l = 0.f;
#pragma unroll
  for (int g = 0; g < 8; ++g) {
    m = fmaxf(m, pmax[(size_t)g * N + n]);
    s += psum[(size_t)g * N + n];
  }
#pragma unroll 8
  for (int s3 = 0; s3 < nsl; ++s3) l += lpart[(size_t)s3 * N + n];
  out_co[n] = (m + s * (1.0f / 256.0f)) / l;
}

// ---------------------------------------------------------------------------
// Kernel 4: spatial gate  x_co = softmax(out_co * C^-0.5)  (one block)
// ---------------------------------------------------------------------------
__global__ __launch_bounds__(1024) void gate_kernel(
    const float* __restrict__ out_co, float* __restrict__ x_co)
{
  const int t = threadIdx.x;
  float z[9];
#pragma unroll
  for (int i2 = 0; i2 < 9; ++i2) z[i2] = out_co[t + 1024 * i2] * 0.0625f;
  float mx = z[0];
#pragma unroll
  for (int i2 = 1; i2 < 9; ++i2) mx = fmaxf(mx, z[i2]);
  for (int off = 32; off > 0; off >>= 1) mx = fmaxf(mx, __shfl_xor(mx, off));
  __shared__ float redm[16], reds[16];
  const int wv = t >> 6, ln = t & 63;
  if (ln == 0) redm[wv] = mx;
  __syncthreads();
  mx = redm[0];
#pragma unroll
  for (int i2 = 1; i2 < 16; ++i2) mx = fmaxf(mx, redm[i2]);

  float e[9]; float sm = 0.f;
#pragma unroll
  for (int i2 = 0; i2 < 9; ++i2) { e[i2] = exp2f((z[i2] - mx) * LOG2E); sm += e[i2]; }
  for (int off = 32; off > 0; off >>= 1) sm += __shfl_xor(sm, off);
  if (ln == 0) reds[wv] = sm;
  __syncthreads();
  sm = 0.f;
#pragma unroll
  for (int i2 = 0; i2 < 16; ++i2) sm += reds[i2];
  const float inv = 1.0f / sm;
#pragma unroll
  for (int i2 = 0; i2 < 9; ++i2) x_co[t + 1024 * i2] = e[i2] * inv;
}

// ---------------------------------------------------------------------------
// Kernel 5: out = x + (1+gamma)*(x_co[n]*(W6@x)[o][n] + b6[o])
// ---------------------------------------------------------------------------
__global__ __launch_bounds__(256) void final_kernel(
    const float* __restrict__ x, const float* __restrict__ W6,
    const float* __restrict__ b6, const float* __restrict__ gamma,
    const float* __restrict__ x_co, float* __restrict__ out)
{
  __shared__ float xs[64][68];
  const int t = threadIdx.x;
  const int n0 = blockIdx.x * 64;
  const int i = t >> 4, j = t & 15;
  const int o0 = blockIdx.y * 64 + i * 4;

  float acc[4][4] = {};
  for (int cc = 0; cc < 4; ++cc) {
    {
      const int row = t >> 2, cq = t & 3;
      const float* src = x + (size_t)(cc * 64 + row) * N + n0 + cq * 16;
      float4 a0 = *(const float4*)(src + 0);
      float4 a1 = *(const float4*)(src + 4);
      float4 a2 = *(const float4*)(src + 8);
      float4 a3 = *(const float4*)(src + 12);
      float* dst = &xs[row][cq * 16];
      *(float4*)(dst + 0) = a0; *(float4*)(dst + 4)  = a1;
      *(float4*)(dst + 8) = a2; *(float4*)(dst + 12) = a3;
    }
    __syncthreads();
#pragma unroll 2
    for (int k4 = 0; k4 < 16; ++k4) {
      float4 wv4[4];
#pragma unroll
      for (int r = 0; r < 4; ++r)
        wv4[r] = *(const float4*)(W6 + (size_t)(o0 + r) * CIN + cc * 64 + k4 * 4);
#pragma unroll
      for (int kk = 0; kk < 4; ++kk) {
        float4 xv = *(const float4*)&xs[k4 * 4 + kk][j * 4];
#pragma unroll
        for (int r = 0; r < 4; ++r) {
          const float wval = ((const float*)&wv4[r])[kk];
          acc[r][0] += wval * xv.x;
          acc[r][1] += wval * xv.y;
          acc[r][2] += wval * xv.z;
          acc[r][3] += wval * xv.w;
        }
      }
    }
    __syncthreads();
  }

  const float g1 = 1.0f + gamma[0];
  const float4 xc = *(const float4*)(x_co + n0 + j * 4);
#pragma unroll
  for (int r = 0; r < 4; ++r) {
    const int o = o0 + r;
    const float bv6 = b6[o];
    const float4 xrow = *(const float4*)(x + (size_t)o * N + n0 + j * 4);
    float4 res;
    res.x = xrow.x + g1 * (xc.x * acc[r][0] + bv6);
    res.y = xrow.y + g1 * (xc.y * acc[r][1] + bv6);
    res.z = xrow.z + g1 * (xc.z * acc[r][2] + bv6);
    res.w = xrow.w + g1 * (xc.w * acc[r][3] + bv6);
    *(float4*)(out + (size_t)o * N + n0 + j * 4) = res;
  }
}

// ---------------------------------------------------------------------------
extern "C" void kernel_launch(void* const* d_in, const int* in_sizes, int n_in,
                              void* d_out, int out_size, void* d_ws, size_t ws_size,
                              hipStream_t stream)
{
  const float* x     = (const float*)d_in[0];
  const float* Wq    = (const float*)d_in[1];
  const float* bq    = (const float*)d_in[2];
  const float* Wk    = (const float*)d_in[3];
  const float* bk    = (const float*)d_in[4];
  const float* Wv    = (const float*)d_in[5];
  const float* bv    = (const float*)d_in[6];
  const float* W6    = (const float*)d_in[7];
  const float* b6    = (const float*)d_in[8];
  const float* gamma = (const float*)d_in[9];
  float* out = (float*)d_out;

  // nsl = 8 -> 1152 attn blocks.  Fallback nsl = 4 if ws too small.
  const size_t fixed = (size_t)N * DQ * 2 * 2        // qT,kT
                     + (size_t)CIN * N * 2            // vG
                     + (size_t)N * 4 * 2              // out_co, x_co
                     + (size_t)8 * N * 4 * 2;         // pmax, psum
  int nsl = 8;
  size_t need8 = fixed + (size_t)8 * NT * 256 * 64 * 2 + (size_t)8 * N * 4;
  if (ws_size < need8) nsl = 4;
  const int sliceIters = (N / nsl) / 32;

  char* ws = (char*)d_ws;
  const size_t OFF_QT = 0;
  const size_t OFF_KT = OFF_QT + (size_t)N * DQ * 2;
  const size_t OFF_V  = OFF_KT + (size_t)N * DQ * 2;
  const size_t OFF_OP = OFF_V  + (size_t)CIN * N * 2;
  const size_t OFF_LP = OFF_OP + (size_t)nsl * NT * 256 * 64 * 2;
  const size_t OFF_PM = OFF_LP + (size_t)nsl * N * 4;
  const size_t OFF_PS = OFF_PM + (size_t)8 * N * 4;
  const size_t OFF_OC = OFF_PS + (size_t)8 * N * 4;
  const size_t OFF_XC = OFF_OC + (size_t)N * 4;

  ushort_t* qT     = (ushort_t*)(ws + OFF_QT);
  ushort_t* kT     = (ushort_t*)(ws + OFF_KT);
  ushort_t* vG     = (ushort_t*)(ws + OFF_V);
  ushort_t* Opart  = (ushort_t*)(ws + OFF_OP);
  float*    lpart  = (float*)(ws + OFF_LP);
  float*    pmax   = (float*)(ws + OFF_PM);
  float*    psum   = (float*)(ws + OFF_PS);
  float*    out_co = (float*)(ws + OFF_OC);
  float*    x_co   = (float*)(ws + OFF_XC);

  qkv_kernel<<<dim3(NT, 5), 256, 0, stream>>>(x, Wq, bq, Wk, bk, Wv, bv, qT, kT, vG);
  attn_kernel<<<dim3(NT, nsl), 256, 0, stream>>>(qT, kT, vG, Opart, lpart, sliceIters);
  cco_partial<<<dim3(NT, 8), 256, 0, stream>>>(Opart, pmax, psum, nsl);
  cco_final<<<N / 256, 256, 0, stream>>>(pmax, psum, lpart, out_co, nsl);
  gate_kernel<<<1, 1024, 0, stream>>>(out_co, x_co);
  final_kernel<<<dim3(NT, 4), 256, 0, stream>>>(x, W6, b6, gamma, x_co, out);
}

// Round 6
// 258.933 us; speedup vs baseline: 1.0771x; 1.0119x over previous
//
#include <hip/hip_runtime.h>

#define N 9216
#define CIN 256
#define DQ 32
#define NT 144                      // N / 64
#define LOG2E 1.44269504088896340736f

typedef short short8 __attribute__((ext_vector_type(8)));   // 8 bf16 in 4 VGPRs
typedef float floatx4 __attribute__((ext_vector_type(4)));
typedef unsigned short ushort_t;

__device__ __forceinline__ ushort_t f2bf(float f) {
  union { float f; unsigned u; } a; a.f = f;
  unsigned u = a.u;
  u += 0x7fffu + ((u >> 16) & 1u);   // round-to-nearest-even
  return (ushort_t)(u >> 16);
}
// cheap round-to-nearest (no RNE tie handling): 2 VALU ops instead of 5.
__device__ __forceinline__ ushort_t f2bf_fast(float f) {
  union { float f; unsigned u; } a; a.f = f;
  return (ushort_t)((a.u + 0x8000u) >> 16);
}
__device__ __forceinline__ float bf2f(ushort_t h) {
  union { unsigned u; float f; } a; a.u = ((unsigned)h) << 16;
  return a.f;
}

// ---------------------------------------------------------------------------
// Kernel 1: q/k/v projections.  grid (144 n-tiles, 5 o-chunks), 256 threads.
// ---------------------------------------------------------------------------
__global__ __launch_bounds__(256) void qkv_kernel(
    const float* __restrict__ x,
    const float* __restrict__ Wq, const float* __restrict__ bq,
    const float* __restrict__ Wk, const float* __restrict__ bk,
    const float* __restrict__ Wv, const float* __restrict__ bv,
    ushort_t* __restrict__ qT, ushort_t* __restrict__ kT,
    ushort_t* __restrict__ vG)
{
  __shared__ float xs[64][68];          // stride 68: 16B-aligned rows, ~2-way banks
  const int t = threadIdx.x;
  const int n0 = blockIdx.x * 64;
  const int oc = blockIdx.y;            // 0..4 ; chunk0 = Wq(32)+Wk(32), 1..4 = Wv
  const int i = t >> 4, j = t & 15;
  const int o0 = oc * 64 + i * 4;

  const float* Wrow[4];
  float bias[4];
#pragma unroll
  for (int r = 0; r < 4; ++r) {
    const int o = o0 + r;
    if (oc == 0) {
      if (o < 32) { Wrow[r] = Wq + o * CIN;        bias[r] = bq[o]; }
      else        { Wrow[r] = Wk + (o - 32) * CIN; bias[r] = bk[o - 32]; }
    } else        { Wrow[r] = Wv + (o - 64) * CIN; bias[r] = bv[o - 64]; }
  }

  float acc[4][4] = {};
  for (int cc = 0; cc < 4; ++cc) {
    {
      const int row = t >> 2, cq = t & 3;
      const float* src = x + (size_t)(cc * 64 + row) * N + n0 + cq * 16;
      float4 a0 = *(const float4*)(src + 0);
      float4 a1 = *(const float4*)(src + 4);
      float4 a2 = *(const float4*)(src + 8);
      float4 a3 = *(const float4*)(src + 12);
      float* dst = &xs[row][cq * 16];
      *(float4*)(dst + 0) = a0; *(float4*)(dst + 4)  = a1;
      *(float4*)(dst + 8) = a2; *(float4*)(dst + 12) = a3;
    }
    __syncthreads();
#pragma unroll 2
    for (int k4 = 0; k4 < 16; ++k4) {
      float4 wv4[4];
#pragma unroll
      for (int r = 0; r < 4; ++r)
        wv4[r] = *(const float4*)(Wrow[r] + cc * 64 + k4 * 4);
#pragma unroll
      for (int kk = 0; kk < 4; ++kk) {
        float4 xv = *(const float4*)&xs[k4 * 4 + kk][j * 4];
#pragma unroll
        for (int r = 0; r < 4; ++r) {
          const float wval = ((const float*)&wv4[r])[kk];
          acc[r][0] += wval * xv.x;
          acc[r][1] += wval * xv.y;
          acc[r][2] += wval * xv.z;
          acc[r][3] += wval * xv.w;
        }
      }
    }
    __syncthreads();
  }

#pragma unroll
  for (int r = 0; r < 4; ++r) {
    const int o = o0 + r;
#pragma unroll
    for (int c = 0; c < 4; ++c) {
      const int n = n0 + j * 4 + c;
      const float val = acc[r][c] + bias[r];
      if (oc == 0) {
        if (o < 32) qT[(size_t)n * DQ + o]        = f2bf(val * LOG2E);
        else        kT[(size_t)n * DQ + (o - 32)] = f2bf(val);
      } else        vG[(size_t)(o - 64) * N + n]  = f2bf(val);
    }
  }
}

// ---------------------------------------------------------------------------
// Kernel 2: flash attention, 32-m tiles.  grid (144 n-tiles, nsl m-slices),
// 256 threads = 4 waves, 64 VGPR + 64 AGPR = 4 waves/SIMD (1024 block slots).
// R5 post-mortem: 1152 blocks / 1024 slots = 2 dispatch rounds -> makespan
// 2x single-block time.  nsl=7 -> 1008 blocks = ONE round (98.4% fill).
// Slices uneven: 288 total iters = base 41, first `rem`=1 slice gets 42.
// ---------------------------------------------------------------------------
__global__ __launch_bounds__(256, 4) void attn_kernel(
    const ushort_t* __restrict__ qT, const ushort_t* __restrict__ kT,
    const ushort_t* __restrict__ vG,
    ushort_t* __restrict__ Opart, float* __restrict__ lpart,
    int base, int rem)
{
  __shared__ ushort_t Pb[2][64][36];    // double-buffered P tile (64n x 32m)

  const int t = threadIdx.x;
  const int w = t >> 6;
  const int lane = t & 63;
  const int quad = lane >> 4;
  const int l15 = lane & 15;
  const int nt = blockIdx.x;
  const int s  = blockIdx.y;
  const int n0 = nt * 64;
  const int sliceIters = base + (s < rem ? 1 : 0);
  const int it0 = s * base + (s < rem ? s : rem);
  const int mbase = it0 * 32;
  const int cw = w * 64;

  // Q A-fragment: invariant over the m-loop. lane holds A[m=l15][k=8*quad+j].
  short8 aq = *(const short8*)(qT + (size_t)(n0 + 16 * w + l15) * DQ + 8 * quad);

  floatx4 acc[4][4];
#pragma unroll
  for (int a2 = 0; a2 < 4; ++a2)
#pragma unroll
    for (int b2 = 0; b2 < 4; ++b2)
      acc[a2][b2] = (floatx4){0.f, 0.f, 0.f, 0.f};
  float lsum[4] = {0.f, 0.f, 0.f, 0.f};
  const floatx4 z4 = {0.f, 0.f, 0.f, 0.f};

  for (int it = 0; it < sliceIters; ++it) {
    const int m0 = mbase + it * 32;

    // S tile (16n x 32m): B-frag lane holds B[k=8*quad+j][n=l15] from kT rows.
    short8 kb0 = *(const short8*)(kT + (size_t)(m0 + l15) * DQ + 8 * quad);
    short8 kb1 = *(const short8*)(kT + (size_t)(m0 + 16 + l15) * DQ + 8 * quad);
    floatx4 s0 = __builtin_amdgcn_mfma_f32_16x16x32_bf16(aq, kb0, z4, 0, 0, 0);
    floatx4 s1 = __builtin_amdgcn_mfma_f32_16x16x32_bf16(aq, kb1, z4, 0, 0, 0);

    // V A-frags from global: A[m=c(l15)][k=m(8*quad+j)], 16B/lane.
    const ushort_t* vb = vG + (size_t)m0 + 8 * quad;
    short8 av0 = *(const short8*)(vb + (size_t)(cw +  0 + l15) * N);
    short8 av1 = *(const short8*)(vb + (size_t)(cw + 16 + l15) * N);
    short8 av2 = *(const short8*)(vb + (size_t)(cw + 32 + l15) * N);
    short8 av3 = *(const short8*)(vb + (size_t)(cw + 48 + l15) * N);

    // exp2 (q pre-scaled by log2e) + sumexp + P -> LDS.
    ushort_t* pb = &Pb[it & 1][0][0];
#pragma unroll
    for (int r = 0; r < 4; ++r) {
      float p0 = exp2f(s0[r]);
      float p1 = exp2f(s1[r]);
      lsum[r] += p0 + p1;
      const int row = 16 * w + 4 * quad + r;
      pb[row * 36 + l15]      = f2bf_fast(p0);
      pb[row * 36 + 16 + l15] = f2bf_fast(p1);
    }
    __syncthreads();   // single barrier/iter: double buffer covers WAR hazard

    // O^T += V * P^T : B-frag lane holds P[n=b2*16+l15][m=8*quad+j].
#pragma unroll
    for (int b2 = 0; b2 < 4; ++b2) {
      const ushort_t* pr = pb + (b2 * 16 + l15) * 36 + 8 * quad;
      union { uint2 u2[2]; short8 v; } u;
      u.u2[0] = *(const uint2*)(pr);
      u.u2[1] = *(const uint2*)(pr + 4);
      const short8 pf = u.v;
      acc[0][b2] = __builtin_amdgcn_mfma_f32_16x16x32_bf16(av0, pf, acc[0][b2], 0, 0, 0);
      acc[1][b2] = __builtin_amdgcn_mfma_f32_16x16x32_bf16(av1, pf, acc[1][b2], 0, 0, 0);
      acc[2][b2] = __builtin_amdgcn_mfma_f32_16x16x32_bf16(av2, pf, acc[2][b2], 0, 0, 0);
      acc[3][b2] = __builtin_amdgcn_mfma_f32_16x16x32_bf16(av3, pf, acc[3][b2], 0, 0, 0);
    }
  }

  // sumexp: reduce over the 16 lanes sharing a quad
#pragma unroll
  for (int r = 0; r < 4; ++r) {
    float v = lsum[r];
    v += __shfl_xor(v, 1);
    v += __shfl_xor(v, 2);
    v += __shfl_xor(v, 4);
    v += __shfl_xor(v, 8);
    lsum[r] = v;
  }
  if (l15 == 0) {
#pragma unroll
    for (int r = 0; r < 4; ++r)
      lpart[(size_t)s * N + n0 + 16 * w + 4 * quad + r] = lsum[r];
  }

  // store O^T partial, layout [s][nt][c:256][n:64]
  const size_t basep = ((size_t)s * NT + nt) * 256;
#pragma unroll
  for (int a2 = 0; a2 < 4; ++a2)
#pragma unroll
    for (int b2 = 0; b2 < 4; ++b2)
#pragma unroll
      for (int r = 0; r < 4; ++r) {
        const int c  = cw + a2 * 16 + 4 * quad + r;
        const int nl = b2 * 16 + l15;
        Opart[(basep + c) * 64 + nl] = f2bf(acc[a2][b2][r]);
      }
}

// ---------------------------------------------------------------------------
// Kernel 3a: combine stage A.  grid (144 n-tiles, 8 c-groups) = 1152 blocks.
// ---------------------------------------------------------------------------
__global__ __launch_bounds__(256) void cco_partial(
    const ushort_t* __restrict__ Opart,
    float* __restrict__ pmax, float* __restrict__ psum, int nsl)
{
  const int nt = blockIdx.x, cy = blockIdx.y;
  const int t = threadIdx.x;
  const int n = t & 63, ci = t >> 6;
  float mx = -3.4e38f, sm = 0.f;
#pragma unroll
  for (int k = 0; k < 8; ++k) {
    const int c = cy * 32 + ci + 4 * k;
    float val = 0.f;
    for (int s2 = 0; s2 < nsl; ++s2)
      val += bf2f(Opart[(((size_t)s2 * NT + nt) * 256 + c) * 64 + n]);
    mx = fmaxf(mx, val);
    sm += val;
  }
  __shared__ float rmx[4][64], rsm[4][64];
  rmx[ci][n] = mx; rsm[ci][n] = sm;
  __syncthreads();
  if (t < 64) {
    const float m2 = fmaxf(fmaxf(rmx[0][t], rmx[1][t]), fmaxf(rmx[2][t], rmx[3][t]));
    const float s2 = rsm[0][t] + rsm[1][t] + rsm[2][t] + rsm[3][t];
    pmax[(size_t)cy * N + nt * 64 + t] = m2;
    psum[(size_t)cy * N + nt * 64 + t] = s2;
  }
}

// ---------------------------------------------------------------------------
// Kernel 3b: combine stage B.  out_co[n] = (max + mean/256) / sumexp.
// 36 blocks x 256 threads, all loads coalesced.
// ---------------------------------------------------------------------------
__global__ __launch_bounds__(256) void cco_final(
    const float* __restrict__ pmax, const float* __restrict__ psum,
    const float* __restrict__ lpart, float* __restrict__ out_co, int nsl)
{
  const int n = blockIdx.x * 256 + threadIdx.x;
  float m = -3.4e38f, s = 0.f, l = 0.f;
#pragma unroll
  for (int g = 0; g < 8; ++g) {
    m = fmaxf(m, pmax[(size_t)g * N + n]);
    s += psum[(size_t)g * N + n];
  }
  for (int s3 = 0; s3 < nsl; ++s3) l += lpart[(size_t)s3 * N + n];
  out_co[n] = (m + s * (1.0f / 256.0f)) / l;
}

// ---------------------------------------------------------------------------
// Kernel 4: spatial gate  x_co = softmax(out_co * C^-0.5)  (one block)
// ---------------------------------------------------------------------------
__global__ __launch_bounds__(1024) void gate_kernel(
    const float* __restrict__ out_co, float* __restrict__ x_co)
{
  const int t = threadIdx.x;
  float z[9];
#pragma unroll
  for (int i2 = 0; i2 < 9; ++i2) z[i2] = out_co[t + 1024 * i2] * 0.0625f;
  float mx = z[0];
#pragma unroll
  for (int i2 = 1; i2 < 9; ++i2) mx = fmaxf(mx, z[i2]);
  for (int off = 32; off > 0; off >>= 1) mx = fmaxf(mx, __shfl_xor(mx, off));
  __shared__ float redm[16], reds[16];
  const int wv = t >> 6, ln = t & 63;
  if (ln == 0) redm[wv] = mx;
  __syncthreads();
  mx = redm[0];
#pragma unroll
  for (int i2 = 1; i2 < 16; ++i2) mx = fmaxf(mx, redm[i2]);

  float e[9]; float sm = 0.f;
#pragma unroll
  for (int i2 = 0; i2 < 9; ++i2) { e[i2] = exp2f((z[i2] - mx) * LOG2E); sm += e[i2]; }
  for (int off = 32; off > 0; off >>= 1) sm += __shfl_xor(sm, off);
  if (ln == 0) reds[wv] = sm;
  __syncthreads();
  sm = 0.f;
#pragma unroll
  for (int i2 = 0; i2 < 16; ++i2) sm += reds[i2];
  const float inv = 1.0f / sm;
#pragma unroll
  for (int i2 = 0; i2 < 9; ++i2) x_co[t + 1024 * i2] = e[i2] * inv;
}

// ---------------------------------------------------------------------------
// Kernel 5: out = x + (1+gamma)*(x_co[n]*(W6@x)[o][n] + b6[o])
// ---------------------------------------------------------------------------
__global__ __launch_bounds__(256) void final_kernel(
    const float* __restrict__ x, const float* __restrict__ W6,
    const float* __restrict__ b6, const float* __restrict__ gamma,
    const float* __restrict__ x_co, float* __restrict__ out)
{
  __shared__ float xs[64][68];
  const int t = threadIdx.x;
  const int n0 = blockIdx.x * 64;
  const int i = t >> 4, j = t & 15;
  const int o0 = blockIdx.y * 64 + i * 4;

  float acc[4][4] = {};
  for (int cc = 0; cc < 4; ++cc) {
    {
      const int row = t >> 2, cq = t & 3;
      const float* src = x + (size_t)(cc * 64 + row) * N + n0 + cq * 16;
      float4 a0 = *(const float4*)(src + 0);
      float4 a1 = *(const float4*)(src + 4);
      float4 a2 = *(const float4*)(src + 8);
      float4 a3 = *(const float4*)(src + 12);
      float* dst = &xs[row][cq * 16];
      *(float4*)(dst + 0) = a0; *(float4*)(dst + 4)  = a1;
      *(float4*)(dst + 8) = a2; *(float4*)(dst + 12) = a3;
    }
    __syncthreads();
#pragma unroll 2
    for (int k4 = 0; k4 < 16; ++k4) {
      float4 wv4[4];
#pragma unroll
      for (int r = 0; r < 4; ++r)
        wv4[r] = *(const float4*)(W6 + (size_t)(o0 + r) * CIN + cc * 64 + k4 * 4);
#pragma unroll
      for (int kk = 0; kk < 4; ++kk) {
        float4 xv = *(const float4*)&xs[k4 * 4 + kk][j * 4];
#pragma unroll
        for (int r = 0; r < 4; ++r) {
          const float wval = ((const float*)&wv4[r])[kk];
          acc[r][0] += wval * xv.x;
          acc[r][1] += wval * xv.y;
          acc[r][2] += wval * xv.z;
          acc[r][3] += wval * xv.w;
        }
      }
    }
    __syncthreads();
  }

  const float g1 = 1.0f + gamma[0];
  const float4 xc = *(const float4*)(x_co + n0 + j * 4);
#pragma unroll
  for (int r = 0; r < 4; ++r) {
    const int o = o0 + r;
    const float bv6 = b6[o];
    const float4 xrow = *(const float4*)(x + (size_t)o * N + n0 + j * 4);
    float4 res;
    res.x = xrow.x + g1 * (xc.x * acc[r][0] + bv6);
    res.y = xrow.y + g1 * (xc.y * acc[r][1] + bv6);
    res.z = xrow.z + g1 * (xc.z * acc[r][2] + bv6);
    res.w = xrow.w + g1 * (xc.w * acc[r][3] + bv6);
    *(float4*)(out + (size_t)o * N + n0 + j * 4) = res;
  }
}

// ---------------------------------------------------------------------------
extern "C" void kernel_launch(void* const* d_in, const int* in_sizes, int n_in,
                              void* d_out, int out_size, void* d_ws, size_t ws_size,
                              hipStream_t stream)
{
  const float* x     = (const float*)d_in[0];
  const float* Wq    = (const float*)d_in[1];
  const float* bq    = (const float*)d_in[2];
  const float* Wk    = (const float*)d_in[3];
  const float* bk    = (const float*)d_in[4];
  const float* Wv    = (const float*)d_in[5];
  const float* bv    = (const float*)d_in[6];
  const float* W6    = (const float*)d_in[7];
  const float* b6    = (const float*)d_in[8];
  const float* gamma = (const float*)d_in[9];
  float* out = (float*)d_out;

  // nsl = 7 -> 1008 attn blocks = ONE co-residency round at 4 blocks/CU
  // (1024 slots).  Uneven slices: 288 iters = 41*7 + 1.
  const size_t fixed = (size_t)N * DQ * 2 * 2        // qT,kT
                     + (size_t)CIN * N * 2            // vG
                     + (size_t)N * 4 * 2              // out_co, x_co
                     + (size_t)8 * N * 4 * 2;         // pmax, psum
  int nsl = 7;
  size_t need = fixed + (size_t)nsl * NT * 256 * 64 * 2 + (size_t)nsl * N * 4;
  if (ws_size < need) nsl = 4;
  const int totIters = N / 32;                        // 288
  const int base = totIters / nsl;
  const int rem  = totIters % nsl;

  char* ws = (char*)d_ws;
  const size_t OFF_QT = 0;
  const size_t OFF_KT = OFF_QT + (size_t)N * DQ * 2;
  const size_t OFF_V  = OFF_KT + (size_t)N * DQ * 2;
  const size_t OFF_OP = OFF_V  + (size_t)CIN * N * 2;
  const size_t OFF_LP = OFF_OP + (size_t)nsl * NT * 256 * 64 * 2;
  const size_t OFF_PM = OFF_LP + (size_t)nsl * N * 4;
  const size_t OFF_PS = OFF_PM + (size_t)8 * N * 4;
  const size_t OFF_OC = OFF_PS + (size_t)8 * N * 4;
  const size_t OFF_XC = OFF_OC + (size_t)N * 4;

  ushort_t* qT     = (ushort_t*)(ws + OFF_QT);
  ushort_t* kT     = (ushort_t*)(ws + OFF_KT);
  ushort_t* vG     = (ushort_t*)(ws + OFF_V);
  ushort_t* Opart  = (ushort_t*)(ws + OFF_OP);
  float*    lpart  = (float*)(ws + OFF_LP);
  float*    pmax   = (float*)(ws + OFF_PM);
  float*    psum   = (float*)(ws + OFF_PS);
  float*    out_co = (float*)(ws + OFF_OC);
  float*    x_co   = (float*)(ws + OFF_XC);

  qkv_kernel<<<dim3(NT, 5), 256, 0, stream>>>(x, Wq, bq, Wk, bk, Wv, bv, qT, kT, vG);
  attn_kernel<<<dim3(NT, nsl), 256, 0, stream>>>(qT, kT, vG, Opart, lpart, base, rem);
  cco_partial<<<dim3(NT, 8), 256, 0, stream>>>(Opart, pmax, psum, nsl);
  cco_final<<<N / 256, 256, 0, stream>>>(pmax, psum, lpart, out_co, nsl);
  gate_kernel<<<1, 1024, 0, stream>>>(out_co, x_co);
  final_kernel<<<dim3(NT, 4), 256, 0, stream>>>(x, W6, b6, gamma, x_co, out);
}

// Round 7
// 246.372 us; speedup vs baseline: 1.1320x; 1.0510x over previous
//
#include <hip/hip_runtime.h>

#define N 9216
#define CIN 256
#define DQ 32
#define NT 144                      // N / 64
#define LOG2E 1.44269504088896340736f

typedef short short8 __attribute__((ext_vector_type(8)));   // 8 bf16 in 4 VGPRs
typedef float floatx4 __attribute__((ext_vector_type(4)));
typedef unsigned short ushort_t;

__device__ __forceinline__ ushort_t f2bf(float f) {
  union { float f; unsigned u; } a; a.f = f;
  unsigned u = a.u;
  u += 0x7fffu + ((u >> 16) & 1u);   // round-to-nearest-even
  return (ushort_t)(u >> 16);
}
// cheap round-to-nearest: 2 VALU ops instead of 5.
__device__ __forceinline__ ushort_t f2bf_fast(float f) {
  union { float f; unsigned u; } a; a.f = f;
  return (ushort_t)((a.u + 0x8000u) >> 16);
}
__device__ __forceinline__ float bf2f(ushort_t h) {
  union { unsigned u; float f; } a; a.u = ((unsigned)h) << 16;
  return a.f;
}

// acc[R][0..3] += W * XV  -- all names literal, no address-taken arrays.
#define ACC4(R, W, XV)                                                   \
  acc[R][0] += (W) * (XV).x;  acc[R][1] += (W) * (XV).y;                 \
  acc[R][2] += (W) * (XV).z;  acc[R][3] += (W) * (XV).w;

// ---------------------------------------------------------------------------
// Kernel 1: q/k/v projections.  grid (144 n-tiles, 5 o-chunks), 256 threads.
// Inner loop rewritten with named registers: the old
// ((const float*)&wv4[r])[kk] pointer-cast indexing risked demoting the W
// tile to scratch (dynamic VGPR indexing) -- suspected cause of the
// unexplained ~70us in the non-attn stack.
// ---------------------------------------------------------------------------
__global__ __launch_bounds__(256) void qkv_kernel(
    const float* __restrict__ x,
    const float* __restrict__ Wq, const float* __restrict__ bq,
    const float* __restrict__ Wk, const float* __restrict__ bk,
    const float* __restrict__ Wv, const float* __restrict__ bv,
    ushort_t* __restrict__ qT, ushort_t* __restrict__ kT,
    ushort_t* __restrict__ vG)
{
  __shared__ float xs[64][68];
  const int t = threadIdx.x;
  const int n0 = blockIdx.x * 64;
  const int oc = blockIdx.y;            // 0..4 ; chunk0 = Wq(32)+Wk(32), 1..4 = Wv
  const int i = t >> 4, j = t & 15;
  const int o0 = oc * 64 + i * 4;

  const float *W0, *W1, *W2, *W3;
  float b0, b1, b2, b3;
  {
    const int o = o0;
    if (oc == 0) {
      if (o < 32) { W0 = Wq + o*CIN; W1 = Wq + (o+1)*CIN; W2 = Wq + (o+2)*CIN; W3 = Wq + (o+3)*CIN;
                    b0 = bq[o]; b1 = bq[o+1]; b2 = bq[o+2]; b3 = bq[o+3]; }
      else        { W0 = Wk + (o-32)*CIN; W1 = Wk + (o-31)*CIN; W2 = Wk + (o-30)*CIN; W3 = Wk + (o-29)*CIN;
                    b0 = bk[o-32]; b1 = bk[o-31]; b2 = bk[o-30]; b3 = bk[o-29]; }
    } else        { W0 = Wv + (o-64)*CIN; W1 = Wv + (o-63)*CIN; W2 = Wv + (o-62)*CIN; W3 = Wv + (o-61)*CIN;
                    b0 = bv[o-64]; b1 = bv[o-63]; b2 = bv[o-62]; b3 = bv[o-61]; }
  }

  float acc[4][4] = {};
  for (int cc = 0; cc < 4; ++cc) {
    {
      const int row = t >> 2, cq = t & 3;
      const float* src = x + (size_t)(cc * 64 + row) * N + n0 + cq * 16;
      float4 a0 = *(const float4*)(src + 0);
      float4 a1 = *(const float4*)(src + 4);
      float4 a2 = *(const float4*)(src + 8);
      float4 a3 = *(const float4*)(src + 12);
      float* dst = &xs[row][cq * 16];
      *(float4*)(dst + 0) = a0; *(float4*)(dst + 4)  = a1;
      *(float4*)(dst + 8) = a2; *(float4*)(dst + 12) = a3;
    }
    __syncthreads();
#pragma unroll 4
    for (int k4 = 0; k4 < 16; ++k4) {
      const float4 w0 = *(const float4*)(W0 + cc * 64 + k4 * 4);
      const float4 w1 = *(const float4*)(W1 + cc * 64 + k4 * 4);
      const float4 w2 = *(const float4*)(W2 + cc * 64 + k4 * 4);
      const float4 w3 = *(const float4*)(W3 + cc * 64 + k4 * 4);
      const float4 x0 = *(const float4*)&xs[k4 * 4 + 0][j * 4];
      const float4 x1 = *(const float4*)&xs[k4 * 4 + 1][j * 4];
      const float4 x2 = *(const float4*)&xs[k4 * 4 + 2][j * 4];
      const float4 x3 = *(const float4*)&xs[k4 * 4 + 3][j * 4];
      ACC4(0, w0.x, x0) ACC4(0, w0.y, x1) ACC4(0, w0.z, x2) ACC4(0, w0.w, x3)
      ACC4(1, w1.x, x0) ACC4(1, w1.y, x1) ACC4(1, w1.z, x2) ACC4(1, w1.w, x3)
      ACC4(2, w2.x, x0) ACC4(2, w2.y, x1) ACC4(2, w2.z, x2) ACC4(2, w2.w, x3)
      ACC4(3, w3.x, x0) ACC4(3, w3.y, x1) ACC4(3, w3.z, x2) ACC4(3, w3.w, x3)
    }
    __syncthreads();
  }

  const float bias[4] = {b0, b1, b2, b3};
#pragma unroll
  for (int r = 0; r < 4; ++r) {
    const int o = o0 + r;
#pragma unroll
    for (int c = 0; c < 4; ++c) {
      const int n = n0 + j * 4 + c;
      const float val = acc[r][c] + bias[r];
      if (oc == 0) {
        if (o < 32) qT[(size_t)n * DQ + o]        = f2bf(val * LOG2E);
        else        kT[(size_t)n * DQ + (o - 32)] = f2bf(val);
      } else        vG[(size_t)(o - 64) * N + n]  = f2bf(val);
    }
  }
}

// ---------------------------------------------------------------------------
// Kernel 2: flash attention, 32-m tiles.  UNCHANGED from R6 (control):
// steady-state plateau ~1.4 block-iters/us/CU; freeze while fixing the rest.
// ---------------------------------------------------------------------------
__global__ __launch_bounds__(256, 4) void attn_kernel(
    const ushort_t* __restrict__ qT, const ushort_t* __restrict__ kT,
    const ushort_t* __restrict__ vG,
    ushort_t* __restrict__ Opart, float* __restrict__ lpart,
    int base, int rem)
{
  __shared__ ushort_t Pb[2][64][36];    // double-buffered P tile (64n x 32m)

  const int t = threadIdx.x;
  const int w = t >> 6;
  const int lane = t & 63;
  const int quad = lane >> 4;
  const int l15 = lane & 15;
  const int nt = blockIdx.x;
  const int s  = blockIdx.y;
  const int n0 = nt * 64;
  const int sliceIters = base + (s < rem ? 1 : 0);
  const int it0 = s * base + (s < rem ? s : rem);
  const int mbase = it0 * 32;
  const int cw = w * 64;

  short8 aq = *(const short8*)(qT + (size_t)(n0 + 16 * w + l15) * DQ + 8 * quad);

  floatx4 acc[4][4];
#pragma unroll
  for (int a2 = 0; a2 < 4; ++a2)
#pragma unroll
    for (int b2 = 0; b2 < 4; ++b2)
      acc[a2][b2] = (floatx4){0.f, 0.f, 0.f, 0.f};
  float lsum[4] = {0.f, 0.f, 0.f, 0.f};
  const floatx4 z4 = {0.f, 0.f, 0.f, 0.f};

  for (int it = 0; it < sliceIters; ++it) {
    const int m0 = mbase + it * 32;

    short8 kb0 = *(const short8*)(kT + (size_t)(m0 + l15) * DQ + 8 * quad);
    short8 kb1 = *(const short8*)(kT + (size_t)(m0 + 16 + l15) * DQ + 8 * quad);
    floatx4 s0 = __builtin_amdgcn_mfma_f32_16x16x32_bf16(aq, kb0, z4, 0, 0, 0);
    floatx4 s1 = __builtin_amdgcn_mfma_f32_16x16x32_bf16(aq, kb1, z4, 0, 0, 0);

    const ushort_t* vb = vG + (size_t)m0 + 8 * quad;
    short8 av0 = *(const short8*)(vb + (size_t)(cw +  0 + l15) * N);
    short8 av1 = *(const short8*)(vb + (size_t)(cw + 16 + l15) * N);
    short8 av2 = *(const short8*)(vb + (size_t)(cw + 32 + l15) * N);
    short8 av3 = *(const short8*)(vb + (size_t)(cw + 48 + l15) * N);

    ushort_t* pb = &Pb[it & 1][0][0];
#pragma unroll
    for (int r = 0; r < 4; ++r) {
      float p0 = exp2f(s0[r]);
      float p1 = exp2f(s1[r]);
      lsum[r] += p0 + p1;
      const int row = 16 * w + 4 * quad + r;
      pb[row * 36 + l15]      = f2bf_fast(p0);
      pb[row * 36 + 16 + l15] = f2bf_fast(p1);
    }
    __syncthreads();

#pragma unroll
    for (int b2 = 0; b2 < 4; ++b2) {
      const ushort_t* pr = pb + (b2 * 16 + l15) * 36 + 8 * quad;
      union { uint2 u2[2]; short8 v; } u;
      u.u2[0] = *(const uint2*)(pr);
      u.u2[1] = *(const uint2*)(pr + 4);
      const short8 pf = u.v;
      acc[0][b2] = __builtin_amdgcn_mfma_f32_16x16x32_bf16(av0, pf, acc[0][b2], 0, 0, 0);
      acc[1][b2] = __builtin_amdgcn_mfma_f32_16x16x32_bf16(av1, pf, acc[1][b2], 0, 0, 0);
      acc[2][b2] = __builtin_amdgcn_mfma_f32_16x16x32_bf16(av2, pf, acc[2][b2], 0, 0, 0);
      acc[3][b2] = __builtin_amdgcn_mfma_f32_16x16x32_bf16(av3, pf, acc[3][b2], 0, 0, 0);
    }
  }

#pragma unroll
  for (int r = 0; r < 4; ++r) {
    float v = lsum[r];
    v += __shfl_xor(v, 1);
    v += __shfl_xor(v, 2);
    v += __shfl_xor(v, 4);
    v += __shfl_xor(v, 8);
    lsum[r] = v;
  }
  if (l15 == 0) {
#pragma unroll
    for (int r = 0; r < 4; ++r)
      lpart[(size_t)s * N + n0 + 16 * w + 4 * quad + r] = lsum[r];
  }

  const size_t basep = ((size_t)s * NT + nt) * 256;
#pragma unroll
  for (int a2 = 0; a2 < 4; ++a2)
#pragma unroll
    for (int b2 = 0; b2 < 4; ++b2)
#pragma unroll
      for (int r = 0; r < 4; ++r) {
        const int c  = cw + a2 * 16 + 4 * quad + r;
        const int nl = b2 * 16 + l15;
        Opart[(basep + c) * 64 + nl] = f2bf(acc[a2][b2][r]);
      }
}

// ---------------------------------------------------------------------------
// Kernel 3a: combine stage A.  grid (144 n-tiles, 8 c-groups) = 1152 blocks.
// NSL is a template param so the slice loop fully unrolls (R5 made it runtime
// and silently dropped the unroll -> dependent HBM-latency chains).
// ---------------------------------------------------------------------------
template<int NSL>
__global__ __launch_bounds__(256) void cco_partial(
    const ushort_t* __restrict__ Opart,
    float* __restrict__ pmax, float* __restrict__ psum)
{
  const int nt = blockIdx.x, cy = blockIdx.y;
  const int t = threadIdx.x;
  const int n = t & 63, ci = t >> 6;
  float mx = -3.4e38f, sm = 0.f;
#pragma unroll
  for (int k = 0; k < 8; ++k) {
    const int c = cy * 32 + ci + 4 * k;
    float val = 0.f;
#pragma unroll
    for (int s2 = 0; s2 < NSL; ++s2)
      val += bf2f(Opart[(((size_t)s2 * NT + nt) * 256 + c) * 64 + n]);
    mx = fmaxf(mx, val);
    sm += val;
  }
  __shared__ float rmx[4][64], rsm[4][64];
  rmx[ci][n] = mx; rsm[ci][n] = sm;
  __syncthreads();
  if (t < 64) {
    const float m2 = fmaxf(fmaxf(rmx[0][t], rmx[1][t]), fmaxf(rmx[2][t], rmx[3][t]));
    const float s2 = rsm[0][t] + rsm[1][t] + rsm[2][t] + rsm[3][t];
    pmax[(size_t)cy * N + nt * 64 + t] = m2;
    psum[(size_t)cy * N + nt * 64 + t] = s2;
  }
}

// ---------------------------------------------------------------------------
// Kernel 3b: combine stage B.  out_co[n] = (max + mean/256) / sumexp.
// ---------------------------------------------------------------------------
template<int NSL>
__global__ __launch_bounds__(256) void cco_final(
    const float* __restrict__ pmax, const float* __restrict__ psum,
    const float* __restrict__ lpart, float* __restrict__ out_co)
{
  const int n = blockIdx.x * 256 + threadIdx.x;
  float m = -3.4e38f, s = 0.f, l = 0.f;
#pragma unroll
  for (int g = 0; g < 8; ++g) {
    m = fmaxf(m, pmax[(size_t)g * N + n]);
    s += psum[(size_t)g * N + n];
  }
#pragma unroll
  for (int s3 = 0; s3 < NSL; ++s3) l += lpart[(size_t)s3 * N + n];
  out_co[n] = (m + s * (1.0f / 256.0f)) / l;
}

// ---------------------------------------------------------------------------
// Kernel 4: spatial gate  x_co = softmax(out_co * C^-0.5)  (one block)
// ---------------------------------------------------------------------------
__global__ __launch_bounds__(1024) void gate_kernel(
    const float* __restrict__ out_co, float* __restrict__ x_co)
{
  const int t = threadIdx.x;
  float z[9];
#pragma unroll
  for (int i2 = 0; i2 < 9; ++i2) z[i2] = out_co[t + 1024 * i2] * 0.0625f;
  float mx = z[0];
#pragma unroll
  for (int i2 = 1; i2 < 9; ++i2) mx = fmaxf(mx, z[i2]);
  for (int off = 32; off > 0; off >>= 1) mx = fmaxf(mx, __shfl_xor(mx, off));
  __shared__ float redm[16], reds[16];
  const int wv = t >> 6, ln = t & 63;
  if (ln == 0) redm[wv] = mx;
  __syncthreads();
  mx = redm[0];
#pragma unroll
  for (int i2 = 1; i2 < 16; ++i2) mx = fmaxf(mx, redm[i2]);

  float e[9]; float sm = 0.f;
#pragma unroll
  for (int i2 = 0; i2 < 9; ++i2) { e[i2] = exp2f((z[i2] - mx) * LOG2E); sm += e[i2]; }
  for (int off = 32; off > 0; off >>= 1) sm += __shfl_xor(sm, off);
  if (ln == 0) reds[wv] = sm;
  __syncthreads();
  sm = 0.f;
#pragma unroll
  for (int i2 = 0; i2 < 16; ++i2) sm += reds[i2];
  const float inv = 1.0f / sm;
#pragma unroll
  for (int i2 = 0; i2 < 9; ++i2) x_co[t + 1024 * i2] = e[i2] * inv;
}

// ---------------------------------------------------------------------------
// Kernel 5: out = x + (1+gamma)*(x_co[n]*(W6@x)[o][n] + b6[o])
// Same named-register inner-loop rewrite as qkv.
// ---------------------------------------------------------------------------
__global__ __launch_bounds__(256) void final_kernel(
    const float* __restrict__ x, const float* __restrict__ W6,
    const float* __restrict__ b6, const float* __restrict__ gamma,
    const float* __restrict__ x_co, float* __restrict__ out)
{
  __shared__ float xs[64][68];
  const int t = threadIdx.x;
  const int n0 = blockIdx.x * 64;
  const int i = t >> 4, j = t & 15;
  const int o0 = blockIdx.y * 64 + i * 4;

  const float* W0 = W6 + (size_t)(o0 + 0) * CIN;
  const float* W1 = W6 + (size_t)(o0 + 1) * CIN;
  const float* W2 = W6 + (size_t)(o0 + 2) * CIN;
  const float* W3 = W6 + (size_t)(o0 + 3) * CIN;

  float acc[4][4] = {};
  for (int cc = 0; cc < 4; ++cc) {
    {
      const int row = t >> 2, cq = t & 3;
      const float* src = x + (size_t)(cc * 64 + row) * N + n0 + cq * 16;
      float4 a0 = *(const float4*)(src + 0);
      float4 a1 = *(const float4*)(src + 4);
      float4 a2 = *(const float4*)(src + 8);
      float4 a3 = *(const float4*)(src + 12);
      float* dst = &xs[row][cq * 16];
      *(float4*)(dst + 0) = a0; *(float4*)(dst + 4)  = a1;
      *(float4*)(dst + 8) = a2; *(float4*)(dst + 12) = a3;
    }
    __syncthreads();
#pragma unroll 4
    for (int k4 = 0; k4 < 16; ++k4) {
      const float4 w0 = *(const float4*)(W0 + cc * 64 + k4 * 4);
      const float4 w1 = *(const float4*)(W1 + cc * 64 + k4 * 4);
      const float4 w2 = *(const float4*)(W2 + cc * 64 + k4 * 4);
      const float4 w3 = *(const float4*)(W3 + cc * 64 + k4 * 4);
      const float4 x0 = *(const float4*)&xs[k4 * 4 + 0][j * 4];
      const float4 x1 = *(const float4*)&xs[k4 * 4 + 1][j * 4];
      const float4 x2 = *(const float4*)&xs[k4 * 4 + 2][j * 4];
      const float4 x3 = *(const float4*)&xs[k4 * 4 + 3][j * 4];
      ACC4(0, w0.x, x0) ACC4(0, w0.y, x1) ACC4(0, w0.z, x2) ACC4(0, w0.w, x3)
      ACC4(1, w1.x, x0) ACC4(1, w1.y, x1) ACC4(1, w1.z, x2) ACC4(1, w1.w, x3)
      ACC4(2, w2.x, x0) ACC4(2, w2.y, x1) ACC4(2, w2.z, x2) ACC4(2, w2.w, x3)
      ACC4(3, w3.x, x0) ACC4(3, w3.y, x1) ACC4(3, w3.z, x2) ACC4(3, w3.w, x3)
    }
    __syncthreads();
  }

  const float g1 = 1.0f + gamma[0];
  const float4 xc = *(const float4*)(x_co + n0 + j * 4);
#pragma unroll
  for (int r = 0; r < 4; ++r) {
    const int o = o0 + r;
    const float bv6 = b6[o];
    const float4 xrow = *(const float4*)(x + (size_t)o * N + n0 + j * 4);
    float4 res;
    res.x = xrow.x + g1 * (xc.x * acc[r][0] + bv6);
    res.y = xrow.y + g1 * (xc.y * acc[r][1] + bv6);
    res.z = xrow.z + g1 * (xc.z * acc[r][2] + bv6);
    res.w = xrow.w + g1 * (xc.w * acc[r][3] + bv6);
    *(float4*)(out + (size_t)o * N + n0 + j * 4) = res;
  }
}

// ---------------------------------------------------------------------------
extern "C" void kernel_launch(void* const* d_in, const int* in_sizes, int n_in,
                              void* d_out, int out_size, void* d_ws, size_t ws_size,
                              hipStream_t stream)
{
  const float* x     = (const float*)d_in[0];
  const float* Wq    = (const float*)d_in[1];
  const float* bq    = (const float*)d_in[2];
  const float* Wk    = (const float*)d_in[3];
  const float* bk    = (const float*)d_in[4];
  const float* Wv    = (const float*)d_in[5];
  const float* bv    = (const float*)d_in[6];
  const float* W6    = (const float*)d_in[7];
  const float* b6    = (const float*)d_in[8];
  const float* gamma = (const float*)d_in[9];
  float* out = (float*)d_out;

  const size_t fixed = (size_t)N * DQ * 2 * 2        // qT,kT
                     + (size_t)CIN * N * 2            // vG
                     + (size_t)N * 4 * 2              // out_co, x_co
                     + (size_t)8 * N * 4 * 2;         // pmax, psum
  int nsl = 7;
  size_t need = fixed + (size_t)nsl * NT * 256 * 64 * 2 + (size_t)nsl * N * 4;
  if (ws_size < need) nsl = 4;
  const int totIters = N / 32;                        // 288
  const int base = totIters / nsl;
  const int rem  = totIters % nsl;

  char* ws = (char*)d_ws;
  const size_t OFF_QT = 0;
  const size_t OFF_KT = OFF_QT + (size_t)N * DQ * 2;
  const size_t OFF_V  = OFF_KT + (size_t)N * DQ * 2;
  const size_t OFF_OP = OFF_V  + (size_t)CIN * N * 2;
  const size_t OFF_LP = OFF_OP + (size_t)nsl * NT * 256 * 64 * 2;
  const size_t OFF_PM = OFF_LP + (size_t)nsl * N * 4;
  const size_t OFF_PS = OFF_PM + (size_t)8 * N * 4;
  const size_t OFF_OC = OFF_PS + (size_t)8 * N * 4;
  const size_t OFF_XC = OFF_OC + (size_t)N * 4;

  ushort_t* qT     = (ushort_t*)(ws + OFF_QT);
  ushort_t* kT     = (ushort_t*)(ws + OFF_KT);
  ushort_t* vG     = (ushort_t*)(ws + OFF_V);
  ushort_t* Opart  = (ushort_t*)(ws + OFF_OP);
  float*    lpart  = (float*)(ws + OFF_LP);
  float*    pmax   = (float*)(ws + OFF_PM);
  float*    psum   = (float*)(ws + OFF_PS);
  float*    out_co = (float*)(ws + OFF_OC);
  float*    x_co   = (float*)(ws + OFF_XC);

  qkv_kernel<<<dim3(NT, 5), 256, 0, stream>>>(x, Wq, bq, Wk, bk, Wv, bv, qT, kT, vG);
  attn_kernel<<<dim3(NT, nsl), 256, 0, stream>>>(qT, kT, vG, Opart, lpart, base, rem);
  if (nsl == 7) {
    cco_partial<7><<<dim3(NT, 8), 256, 0, stream>>>(Opart, pmax, psum);
    cco_final<7><<<N / 256, 256, 0, stream>>>(pmax, psum, lpart, out_co);
  } else {
    cco_partial<4><<<dim3(NT, 8), 256, 0, stream>>>(Opart, pmax, psum);
    cco_final<4><<<N / 256, 256, 0, stream>>>(pmax, psum, lpart, out_co);
  }
  gate_kernel<<<1, 1024, 0, stream>>>(out_co, x_co);
  final_kernel<<<dim3(NT, 4), 256, 0, stream>>>(x, W6, b6, gamma, x_co, out);
}

// Round 8
// 243.975 us; speedup vs baseline: 1.1431x; 1.0098x over previous
//
#include <hip/hip_runtime.h>

#define N 9216
#define CIN 256
#define DQ 32
#define NT 144                      // N / 64
#define LOG2E 1.44269504088896340736f

typedef short short8 __attribute__((ext_vector_type(8)));   // 8 bf16 in 4 VGPRs
typedef float floatx4 __attribute__((ext_vector_type(4)));
typedef unsigned short ushort_t;

__device__ __forceinline__ ushort_t f2bf(float f) {
  union { float f; unsigned u; } a; a.f = f;
  unsigned u = a.u;
  u += 0x7fffu + ((u >> 16) & 1u);   // round-to-nearest-even
  return (ushort_t)(u >> 16);
}
// cheap round-to-nearest: 2 VALU ops instead of 5.
__device__ __forceinline__ ushort_t f2bf_fast(float f) {
  union { float f; unsigned u; } a; a.f = f;
  return (ushort_t)((a.u + 0x8000u) >> 16);
}
__device__ __forceinline__ float bf2f(ushort_t h) {
  union { unsigned u; float f; } a; a.u = ((unsigned)h) << 16;
  return a.f;
}

// acc[R][0..3] += W * XV  -- all names literal, no address-taken arrays.
#define ACC4(R, W, XV)                                                   \
  acc[R][0] += (W) * (XV).x;  acc[R][1] += (W) * (XV).y;                 \
  acc[R][2] += (W) * (XV).z;  acc[R][3] += (W) * (XV).w;

// ---------------------------------------------------------------------------
// Kernel 1: q/k/v projections.  grid (144 n-tiles, 5 o-chunks), 256 threads.
// Block (0,0) thread 0 also zero-inits the gate softmax accumulator (same-
// stream ordering makes it visible to cco's atomicAdd).
// ---------------------------------------------------------------------------
__global__ __launch_bounds__(256) void qkv_kernel(
    const float* __restrict__ x,
    const float* __restrict__ Wq, const float* __restrict__ bq,
    const float* __restrict__ Wk, const float* __restrict__ bk,
    const float* __restrict__ Wv, const float* __restrict__ bv,
    ushort_t* __restrict__ qT, ushort_t* __restrict__ kT,
    ushort_t* __restrict__ vG, float* __restrict__ sumExp)
{
  if (blockIdx.x == 0 && blockIdx.y == 0 && threadIdx.x == 0) *sumExp = 0.f;

  __shared__ float xs[64][68];
  const int t = threadIdx.x;
  const int n0 = blockIdx.x * 64;
  const int oc = blockIdx.y;            // 0..4 ; chunk0 = Wq(32)+Wk(32), 1..4 = Wv
  const int i = t >> 4, j = t & 15;
  const int o0 = oc * 64 + i * 4;

  const float *W0, *W1, *W2, *W3;
  float b0, b1, b2, b3;
  {
    const int o = o0;
    if (oc == 0) {
      if (o < 32) { W0 = Wq + o*CIN; W1 = Wq + (o+1)*CIN; W2 = Wq + (o+2)*CIN; W3 = Wq + (o+3)*CIN;
                    b0 = bq[o]; b1 = bq[o+1]; b2 = bq[o+2]; b3 = bq[o+3]; }
      else        { W0 = Wk + (o-32)*CIN; W1 = Wk + (o-31)*CIN; W2 = Wk + (o-30)*CIN; W3 = Wk + (o-29)*CIN;
                    b0 = bk[o-32]; b1 = bk[o-31]; b2 = bk[o-30]; b3 = bk[o-29]; }
    } else        { W0 = Wv + (o-64)*CIN; W1 = Wv + (o-63)*CIN; W2 = Wv + (o-62)*CIN; W3 = Wv + (o-61)*CIN;
                    b0 = bv[o-64]; b1 = bv[o-63]; b2 = bv[o-62]; b3 = bv[o-61]; }
  }

  float acc[4][4] = {};
  for (int cc = 0; cc < 4; ++cc) {
    {
      const int row = t >> 2, cq = t & 3;
      const float* src = x + (size_t)(cc * 64 + row) * N + n0 + cq * 16;
      float4 a0 = *(const float4*)(src + 0);
      float4 a1 = *(const float4*)(src + 4);
      float4 a2 = *(const float4*)(src + 8);
      float4 a3 = *(const float4*)(src + 12);
      float* dst = &xs[row][cq * 16];
      *(float4*)(dst + 0) = a0; *(float4*)(dst + 4)  = a1;
      *(float4*)(dst + 8) = a2; *(float4*)(dst + 12) = a3;
    }
    __syncthreads();
#pragma unroll 4
    for (int k4 = 0; k4 < 16; ++k4) {
      const float4 w0 = *(const float4*)(W0 + cc * 64 + k4 * 4);
      const float4 w1 = *(const float4*)(W1 + cc * 64 + k4 * 4);
      const float4 w2 = *(const float4*)(W2 + cc * 64 + k4 * 4);
      const float4 w3 = *(const float4*)(W3 + cc * 64 + k4 * 4);
      const float4 x0 = *(const float4*)&xs[k4 * 4 + 0][j * 4];
      const float4 x1 = *(const float4*)&xs[k4 * 4 + 1][j * 4];
      const float4 x2 = *(const float4*)&xs[k4 * 4 + 2][j * 4];
      const float4 x3 = *(const float4*)&xs[k4 * 4 + 3][j * 4];
      ACC4(0, w0.x, x0) ACC4(0, w0.y, x1) ACC4(0, w0.z, x2) ACC4(0, w0.w, x3)
      ACC4(1, w1.x, x0) ACC4(1, w1.y, x1) ACC4(1, w1.z, x2) ACC4(1, w1.w, x3)
      ACC4(2, w2.x, x0) ACC4(2, w2.y, x1) ACC4(2, w2.z, x2) ACC4(2, w2.w, x3)
      ACC4(3, w3.x, x0) ACC4(3, w3.y, x1) ACC4(3, w3.z, x2) ACC4(3, w3.w, x3)
    }
    __syncthreads();
  }

  const float bias[4] = {b0, b1, b2, b3};
#pragma unroll
  for (int r = 0; r < 4; ++r) {
    const int o = o0 + r;
#pragma unroll
    for (int c = 0; c < 4; ++c) {
      const int n = n0 + j * 4 + c;
      const float val = acc[r][c] + bias[r];
      if (oc == 0) {
        if (o < 32) qT[(size_t)n * DQ + o]        = f2bf(val * LOG2E);
        else        kT[(size_t)n * DQ + (o - 32)] = f2bf(val);
      } else        vG[(size_t)(o - 64) * N + n]  = f2bf(val);
    }
  }
}

// ---------------------------------------------------------------------------
// Kernel 2: flash attention, 32-m tiles.  UNCHANGED (control).
// ---------------------------------------------------------------------------
__global__ __launch_bounds__(256, 4) void attn_kernel(
    const ushort_t* __restrict__ qT, const ushort_t* __restrict__ kT,
    const ushort_t* __restrict__ vG,
    ushort_t* __restrict__ Opart, float* __restrict__ lpart,
    int base, int rem)
{
  __shared__ ushort_t Pb[2][64][36];    // double-buffered P tile (64n x 32m)

  const int t = threadIdx.x;
  const int w = t >> 6;
  const int lane = t & 63;
  const int quad = lane >> 4;
  const int l15 = lane & 15;
  const int nt = blockIdx.x;
  const int s  = blockIdx.y;
  const int n0 = nt * 64;
  const int sliceIters = base + (s < rem ? 1 : 0);
  const int it0 = s * base + (s < rem ? s : rem);
  const int mbase = it0 * 32;
  const int cw = w * 64;

  short8 aq = *(const short8*)(qT + (size_t)(n0 + 16 * w + l15) * DQ + 8 * quad);

  floatx4 acc[4][4];
#pragma unroll
  for (int a2 = 0; a2 < 4; ++a2)
#pragma unroll
    for (int b2 = 0; b2 < 4; ++b2)
      acc[a2][b2] = (floatx4){0.f, 0.f, 0.f, 0.f};
  float lsum[4] = {0.f, 0.f, 0.f, 0.f};
  const floatx4 z4 = {0.f, 0.f, 0.f, 0.f};

  for (int it = 0; it < sliceIters; ++it) {
    const int m0 = mbase + it * 32;

    short8 kb0 = *(const short8*)(kT + (size_t)(m0 + l15) * DQ + 8 * quad);
    short8 kb1 = *(const short8*)(kT + (size_t)(m0 + 16 + l15) * DQ + 8 * quad);
    floatx4 s0 = __builtin_amdgcn_mfma_f32_16x16x32_bf16(aq, kb0, z4, 0, 0, 0);
    floatx4 s1 = __builtin_amdgcn_mfma_f32_16x16x32_bf16(aq, kb1, z4, 0, 0, 0);

    const ushort_t* vb = vG + (size_t)m0 + 8 * quad;
    short8 av0 = *(const short8*)(vb + (size_t)(cw +  0 + l15) * N);
    short8 av1 = *(const short8*)(vb + (size_t)(cw + 16 + l15) * N);
    short8 av2 = *(const short8*)(vb + (size_t)(cw + 32 + l15) * N);
    short8 av3 = *(const short8*)(vb + (size_t)(cw + 48 + l15) * N);

    ushort_t* pb = &Pb[it & 1][0][0];
#pragma unroll
    for (int r = 0; r < 4; ++r) {
      float p0 = exp2f(s0[r]);
      float p1 = exp2f(s1[r]);
      lsum[r] += p0 + p1;
      const int row = 16 * w + 4 * quad + r;
      pb[row * 36 + l15]      = f2bf_fast(p0);
      pb[row * 36 + 16 + l15] = f2bf_fast(p1);
    }
    __syncthreads();

#pragma unroll
    for (int b2 = 0; b2 < 4; ++b2) {
      const ushort_t* pr = pb + (b2 * 16 + l15) * 36 + 8 * quad;
      union { uint2 u2[2]; short8 v; } u;
      u.u2[0] = *(const uint2*)(pr);
      u.u2[1] = *(const uint2*)(pr + 4);
      const short8 pf = u.v;
      acc[0][b2] = __builtin_amdgcn_mfma_f32_16x16x32_bf16(av0, pf, acc[0][b2], 0, 0, 0);
      acc[1][b2] = __builtin_amdgcn_mfma_f32_16x16x32_bf16(av1, pf, acc[1][b2], 0, 0, 0);
      acc[2][b2] = __builtin_amdgcn_mfma_f32_16x16x32_bf16(av2, pf, acc[2][b2], 0, 0, 0);
      acc[3][b2] = __builtin_amdgcn_mfma_f32_16x16x32_bf16(av3, pf, acc[3][b2], 0, 0, 0);
    }
  }

#pragma unroll
  for (int r = 0; r < 4; ++r) {
    float v = lsum[r];
    v += __shfl_xor(v, 1);
    v += __shfl_xor(v, 2);
    v += __shfl_xor(v, 4);
    v += __shfl_xor(v, 8);
    lsum[r] = v;
  }
  if (l15 == 0) {
#pragma unroll
    for (int r = 0; r < 4; ++r)
      lpart[(size_t)s * N + n0 + 16 * w + 4 * quad + r] = lsum[r];
  }

  const size_t basep = ((size_t)s * NT + nt) * 256;
#pragma unroll
  for (int a2 = 0; a2 < 4; ++a2)
#pragma unroll
    for (int b2 = 0; b2 < 4; ++b2)
#pragma unroll
      for (int r = 0; r < 4; ++r) {
        const int c  = cw + a2 * 16 + 4 * quad + r;
        const int nl = b2 * 16 + l15;
        Opart[(basep + c) * 64 + nl] = f2bf(acc[a2][b2][r]);
      }
}

// ---------------------------------------------------------------------------
// Kernel 3: fused combine + gate-exp.  grid 144 blocks x 1024 threads.
// Per n: sum Opart over slices per c, max_c + mean_c, /sumexp(l), then
// e = exp2(out_co/16 * log2e) WITHOUT max-subtraction (|out_co/16| <~ 0.2,
// fp32-safe) and one atomicAdd of the block's partial sum(e).
// Replaces cco_partial + cco_final + gate_kernel (3 launches -> 1).
// ---------------------------------------------------------------------------
template<int NSL>
__global__ __launch_bounds__(1024) void cco_kernel(
    const ushort_t* __restrict__ Opart, const float* __restrict__ lpart,
    float* __restrict__ e_buf, float* __restrict__ sumExp)
{
  const int nt = blockIdx.x;
  const int t = threadIdx.x;
  const int n = t & 63, ci = t >> 6;   // ci in [0,16)
  float mx = -3.4e38f, sm = 0.f;
#pragma unroll
  for (int k = 0; k < 16; ++k) {
    const int c = ci * 16 + k;
    float val = 0.f;
#pragma unroll
    for (int s2 = 0; s2 < NSL; ++s2)
      val += bf2f(Opart[(((size_t)s2 * NT + nt) * 256 + c) * 64 + n]);
    mx = fmaxf(mx, val);
    sm += val;
  }
  __shared__ float rmx[16][64], rsm[16][64];
  rmx[ci][n] = mx; rsm[ci][n] = sm;
  __syncthreads();
  if (t < 64) {
    float m = rmx[0][t], s = rsm[0][t];
#pragma unroll
    for (int g = 1; g < 16; ++g) { m = fmaxf(m, rmx[g][t]); s += rsm[g][t]; }
    float l = 0.f;
#pragma unroll
    for (int s3 = 0; s3 < NSL; ++s3) l += lpart[(size_t)s3 * N + nt * 64 + t];
    const float oc = (m + s * (1.0f / 256.0f)) / l;
    const float ev = exp2f(oc * (0.0625f * LOG2E));
    e_buf[nt * 64 + t] = ev;
    float vs = ev;
    vs += __shfl_xor(vs, 1);  vs += __shfl_xor(vs, 2);
    vs += __shfl_xor(vs, 4);  vs += __shfl_xor(vs, 8);
    vs += __shfl_xor(vs, 16); vs += __shfl_xor(vs, 32);
    if (t == 0) atomicAdd(sumExp, vs);
  }
}

// ---------------------------------------------------------------------------
// Kernel 4: out = x + (1+gamma)*(x_co[n]*(W6@x)[o][n] + b6[o]),
// x_co[n] = e_buf[n] / *sumExp computed on the fly.
// ---------------------------------------------------------------------------
__global__ __launch_bounds__(256) void final_kernel(
    const float* __restrict__ x, const float* __restrict__ W6,
    const float* __restrict__ b6, const float* __restrict__ gamma,
    const float* __restrict__ e_buf, const float* __restrict__ sumExp,
    float* __restrict__ out)
{
  __shared__ float xs[64][68];
  const int t = threadIdx.x;
  const int n0 = blockIdx.x * 64;
  const int i = t >> 4, j = t & 15;
  const int o0 = blockIdx.y * 64 + i * 4;

  const float* W0 = W6 + (size_t)(o0 + 0) * CIN;
  const float* W1 = W6 + (size_t)(o0 + 1) * CIN;
  const float* W2 = W6 + (size_t)(o0 + 2) * CIN;
  const float* W3 = W6 + (size_t)(o0 + 3) * CIN;

  float acc[4][4] = {};
  for (int cc = 0; cc < 4; ++cc) {
    {
      const int row = t >> 2, cq = t & 3;
      const float* src = x + (size_t)(cc * 64 + row) * N + n0 + cq * 16;
      float4 a0 = *(const float4*)(src + 0);
      float4 a1 = *(const float4*)(src + 4);
      float4 a2 = *(const float4*)(src + 8);
      float4 a3 = *(const float4*)(src + 12);
      float* dst = &xs[row][cq * 16];
      *(float4*)(dst + 0) = a0; *(float4*)(dst + 4)  = a1;
      *(float4*)(dst + 8) = a2; *(float4*)(dst + 12) = a3;
    }
    __syncthreads();
#pragma unroll 4
    for (int k4 = 0; k4 < 16; ++k4) {
      const float4 w0 = *(const float4*)(W0 + cc * 64 + k4 * 4);
      const float4 w1 = *(const float4*)(W1 + cc * 64 + k4 * 4);
      const float4 w2 = *(const float4*)(W2 + cc * 64 + k4 * 4);
      const float4 w3 = *(const float4*)(W3 + cc * 64 + k4 * 4);
      const float4 x0 = *(const float4*)&xs[k4 * 4 + 0][j * 4];
      const float4 x1 = *(const float4*)&xs[k4 * 4 + 1][j * 4];
      const float4 x2 = *(const float4*)&xs[k4 * 4 + 2][j * 4];
      const float4 x3 = *(const float4*)&xs[k4 * 4 + 3][j * 4];
      ACC4(0, w0.x, x0) ACC4(0, w0.y, x1) ACC4(0, w0.z, x2) ACC4(0, w0.w, x3)
      ACC4(1, w1.x, x0) ACC4(1, w1.y, x1) ACC4(1, w1.z, x2) ACC4(1, w1.w, x3)
      ACC4(2, w2.x, x0) ACC4(2, w2.y, x1) ACC4(2, w2.z, x2) ACC4(2, w2.w, x3)
      ACC4(3, w3.x, x0) ACC4(3, w3.y, x1) ACC4(3, w3.z, x2) ACC4(3, w3.w, x3)
    }
    __syncthreads();
  }

  const float g1 = 1.0f + gamma[0];
  const float inv = 1.0f / sumExp[0];
  float4 xc = *(const float4*)(e_buf + n0 + j * 4);
  xc.x *= inv; xc.y *= inv; xc.z *= inv; xc.w *= inv;
#pragma unroll
  for (int r = 0; r < 4; ++r) {
    const int o = o0 + r;
    const float bv6 = b6[o];
    const float4 xrow = *(const float4*)(x + (size_t)o * N + n0 + j * 4);
    float4 res;
    res.x = xrow.x + g1 * (xc.x * acc[r][0] + bv6);
    res.y = xrow.y + g1 * (xc.y * acc[r][1] + bv6);
    res.z = xrow.z + g1 * (xc.z * acc[r][2] + bv6);
    res.w = xrow.w + g1 * (xc.w * acc[r][3] + bv6);
    *(float4*)(out + (size_t)o * N + n0 + j * 4) = res;
  }
}

// ---------------------------------------------------------------------------
extern "C" void kernel_launch(void* const* d_in, const int* in_sizes, int n_in,
                              void* d_out, int out_size, void* d_ws, size_t ws_size,
                              hipStream_t stream)
{
  const float* x     = (const float*)d_in[0];
  const float* Wq    = (const float*)d_in[1];
  const float* bq    = (const float*)d_in[2];
  const float* Wk    = (const float*)d_in[3];
  const float* bk    = (const float*)d_in[4];
  const float* Wv    = (const float*)d_in[5];
  const float* bv    = (const float*)d_in[6];
  const float* W6    = (const float*)d_in[7];
  const float* b6    = (const float*)d_in[8];
  const float* gamma = (const float*)d_in[9];
  float* out = (float*)d_out;

  const size_t fixed = (size_t)N * DQ * 2 * 2        // qT,kT
                     + (size_t)CIN * N * 2            // vG
                     + (size_t)N * 4                  // e_buf
                     + 256;                           // sumExp (+pad)
  int nsl = 7;
  size_t need = fixed + (size_t)nsl * NT * 256 * 64 * 2 + (size_t)nsl * N * 4;
  if (ws_size < need) nsl = 4;
  const int totIters = N / 32;                        // 288
  const int base = totIters / nsl;
  const int rem  = totIters % nsl;

  char* ws = (char*)d_ws;
  const size_t OFF_QT = 0;
  const size_t OFF_KT = OFF_QT + (size_t)N * DQ * 2;
  const size_t OFF_V  = OFF_KT + (size_t)N * DQ * 2;
  const size_t OFF_OP = OFF_V  + (size_t)CIN * N * 2;
  const size_t OFF_LP = OFF_OP + (size_t)nsl * NT * 256 * 64 * 2;
  const size_t OFF_EB = OFF_LP + (size_t)nsl * N * 4;
  const size_t OFF_SE = OFF_EB + (size_t)N * 4;

  ushort_t* qT     = (ushort_t*)(ws + OFF_QT);
  ushort_t* kT     = (ushort_t*)(ws + OFF_KT);
  ushort_t* vG     = (ushort_t*)(ws + OFF_V);
  ushort_t* Opart  = (ushort_t*)(ws + OFF_OP);
  float*    lpart  = (float*)(ws + OFF_LP);
  float*    e_buf  = (float*)(ws + OFF_EB);
  float*    sumExp = (float*)(ws + OFF_SE);

  qkv_kernel<<<dim3(NT, 5), 256, 0, stream>>>(x, Wq, bq, Wk, bk, Wv, bv, qT, kT, vG, sumExp);
  attn_kernel<<<dim3(NT, nsl), 256, 0, stream>>>(qT, kT, vG, Opart, lpart, base, rem);
  if (nsl == 7) cco_kernel<7><<<NT, 1024, 0, stream>>>(Opart, lpart, e_buf, sumExp);
  else          cco_kernel<4><<<NT, 1024, 0, stream>>>(Opart, lpart, e_buf, sumExp);
  final_kernel<<<dim3(NT, 4), 256, 0, stream>>>(x, W6, b6, gamma, e_buf, sumExp, out);
}

// Round 9
// 220.528 us; speedup vs baseline: 1.2647x; 1.1063x over previous
//
#include <hip/hip_runtime.h>

#define N 9216
#define CIN 256
#define DQ 32
#define NT 144                      // N / 64
#define LOG2E 1.44269504088896340736f

typedef short short8 __attribute__((ext_vector_type(8)));   // 8 bf16 in 4 VGPRs
typedef float floatx4 __attribute__((ext_vector_type(4)));
typedef unsigned short ushort_t;

__device__ __forceinline__ ushort_t f2bf(float f) {
  union { float f; unsigned u; } a; a.f = f;
  unsigned u = a.u;
  u += 0x7fffu + ((u >> 16) & 1u);   // round-to-nearest-even
  return (ushort_t)(u >> 16);
}
// cheap round-to-nearest: 2 VALU ops instead of 5.
__device__ __forceinline__ ushort_t f2bf_fast(float f) {
  union { float f; unsigned u; } a; a.f = f;
  return (ushort_t)((a.u + 0x8000u) >> 16);
}
__device__ __forceinline__ float bf2f(ushort_t h) {
  union { unsigned u; float f; } a; a.u = ((unsigned)h) << 16;
  return a.f;
}
// pack two floats -> one uint of 2 bf16 (lo = c, hi = c1)
__device__ __forceinline__ unsigned pack2(float lo, float hi) {
  return ((unsigned)f2bf_fast(hi) << 16) | (unsigned)f2bf_fast(lo);
}
// 8 consecutive fp32 -> bf16x8 A-fragment
__device__ __forceinline__ short8 mk_bf16x8(const float* p) {
  float4 f0 = *(const float4*)(p);
  float4 f1 = *(const float4*)(p + 4);
  union { unsigned u[4]; short8 v; } r;
  r.u[0] = pack2(f0.x, f0.y);
  r.u[1] = pack2(f0.z, f0.w);
  r.u[2] = pack2(f1.x, f1.y);
  r.u[3] = pack2(f1.z, f1.w);
  return r.v;
}

// ---------------------------------------------------------------------------
// Shared staging: x tile (256 c x 64 n) -> LDS bf16 xbT[n][k=c] (B-frag
// layout: row n, k contiguous; +8 ushort pad -> 528 B row stride, 16B-aligned
// reads).  Thread t: c-pair p = t&31 (per 64-c chunk), n-group ng = t>>5;
// packs (c, c+1) into b32 writes -- consecutive uints across lanes, no bank
// conflicts.
// ---------------------------------------------------------------------------
#define XBT_STRIDE 264   // ushorts per row (256 + 8 pad); 132 uints

__device__ __forceinline__ void stage_x_tile(
    const float* __restrict__ x, int n0, int t, ushort_t (*xbT)[XBT_STRIDE])
{
  const int p = t & 31, ng = t >> 5;          // ng in [0,8)
  unsigned* base = (unsigned*)&xbT[0][0] + (size_t)(ng * 8) * 132;
#pragma unroll
  for (int cc = 0; cc < 4; ++cc) {
    const int c = cc * 64 + 2 * p;
    const float* r0 = x + (size_t)c * N + n0 + ng * 8;
    const float* r1 = r0 + N;
    float4 a0 = *(const float4*)(r0);
    float4 a1 = *(const float4*)(r0 + 4);
    float4 b0 = *(const float4*)(r1);
    float4 b1 = *(const float4*)(r1 + 4);
    unsigned* d = base + (cc * 32 + p);
    d[0 * 132] = pack2(a0.x, b0.x);
    d[1 * 132] = pack2(a0.y, b0.y);
    d[2 * 132] = pack2(a0.z, b0.z);
    d[3 * 132] = pack2(a0.w, b0.w);
    d[4 * 132] = pack2(a1.x, b1.x);
    d[5 * 132] = pack2(a1.y, b1.y);
    d[6 * 132] = pack2(a1.z, b1.z);
    d[7 * 132] = pack2(a1.w, b1.w);
  }
}

// ---------------------------------------------------------------------------
// Kernel 1: q/k/v projections via bf16 MFMA.  grid (144 n-tiles, 5 o-chunks),
// 256 threads = 4 waves; wave w computes o-strip [oc*64+16w, +16) x 64 n,
// K = 256 in 8 MFMA k-steps.  A-frags built on the fly from fp32 W rows
// (L2-hot); B-frags = ds_read_b128 from xbT.  Replaces the fp32 VALU GEMM
// (R8 ledger: qkv+final ~ 129 us residual; MFMA floor is ~2 us each).
// ---------------------------------------------------------------------------
__global__ __launch_bounds__(256) void qkv_mfma(
    const float* __restrict__ x,
    const float* __restrict__ Wq, const float* __restrict__ bq,
    const float* __restrict__ Wk, const float* __restrict__ bk,
    const float* __restrict__ Wv, const float* __restrict__ bv,
    ushort_t* __restrict__ qT, ushort_t* __restrict__ kT,
    ushort_t* __restrict__ vG, float* __restrict__ sumExp)
{
  if (blockIdx.x == 0 && blockIdx.y == 0 && threadIdx.x == 0) *sumExp = 0.f;

  __shared__ ushort_t xbT[64][XBT_STRIDE];
  const int t = threadIdx.x;
  const int n0 = blockIdx.x * 64;
  const int oc = blockIdx.y;                 // 0: q(32)+k(32); 1..4: v
  const int w = t >> 6, lane = t & 63;
  const int quad = lane >> 4, l15 = lane & 15;

  stage_x_tile(x, n0, t, xbT);
  __syncthreads();

  const int obase = oc * 64 + w * 16;
  const int oA = obase + l15;                // A-frag row (m = l15)
  const float* Arow;
  if (oc == 0) Arow = (obase < 32) ? (Wq + (size_t)oA * CIN)
                                   : (Wk + (size_t)(oA - 32) * CIN);
  else         Arow = Wv + (size_t)(oA - 64) * CIN;

  floatx4 acc[4];
#pragma unroll
  for (int b2 = 0; b2 < 4; ++b2) acc[b2] = (floatx4){0.f, 0.f, 0.f, 0.f};

#pragma unroll
  for (int ks = 0; ks < 8; ++ks) {
    const short8 af = mk_bf16x8(Arow + ks * 32 + 8 * quad);
#pragma unroll
    for (int b2 = 0; b2 < 4; ++b2) {
      const short8 bf = *(const short8*)&xbT[b2 * 16 + l15][ks * 32 + 8 * quad];
      acc[b2] = __builtin_amdgcn_mfma_f32_16x16x32_bf16(af, bf, acc[b2], 0, 0, 0);
    }
  }

  // Epilogue.  C-layout: col = l15 (n within subtile), row = 4*quad + r (o).
#pragma unroll
  for (int b2 = 0; b2 < 4; ++b2) {
    const int n = n0 + b2 * 16 + l15;
#pragma unroll
    for (int r = 0; r < 4; ++r) {
      const int o = obase + 4 * quad + r;
      const float val = acc[b2][r];
      if (oc == 0) {
        if (o < 32) qT[(size_t)n * DQ + o]        = f2bf((val + bq[o]) * LOG2E);
        else        kT[(size_t)n * DQ + (o - 32)] = f2bf(val + bk[o - 32]);
      } else        vG[(size_t)(o - 64) * N + n]  = f2bf(val + bv[o - 64]);
    }
  }
}

// ---------------------------------------------------------------------------
// Kernel 2: flash attention, 32-m tiles.  UNCHANGED (control).
// ---------------------------------------------------------------------------
__global__ __launch_bounds__(256, 4) void attn_kernel(
    const ushort_t* __restrict__ qT, const ushort_t* __restrict__ kT,
    const ushort_t* __restrict__ vG,
    ushort_t* __restrict__ Opart, float* __restrict__ lpart,
    int base, int rem)
{
  __shared__ ushort_t Pb[2][64][36];    // double-buffered P tile (64n x 32m)

  const int t = threadIdx.x;
  const int w = t >> 6;
  const int lane = t & 63;
  const int quad = lane >> 4;
  const int l15 = lane & 15;
  const int nt = blockIdx.x;
  const int s  = blockIdx.y;
  const int n0 = nt * 64;
  const int sliceIters = base + (s < rem ? 1 : 0);
  const int it0 = s * base + (s < rem ? s : rem);
  const int mbase = it0 * 32;
  const int cw = w * 64;

  short8 aq = *(const short8*)(qT + (size_t)(n0 + 16 * w + l15) * DQ + 8 * quad);

  floatx4 acc[4][4];
#pragma unroll
  for (int a2 = 0; a2 < 4; ++a2)
#pragma unroll
    for (int b2 = 0; b2 < 4; ++b2)
      acc[a2][b2] = (floatx4){0.f, 0.f, 0.f, 0.f};
  float lsum[4] = {0.f, 0.f, 0.f, 0.f};
  const floatx4 z4 = {0.f, 0.f, 0.f, 0.f};

  for (int it = 0; it < sliceIters; ++it) {
    const int m0 = mbase + it * 32;

    short8 kb0 = *(const short8*)(kT + (size_t)(m0 + l15) * DQ + 8 * quad);
    short8 kb1 = *(const short8*)(kT + (size_t)(m0 + 16 + l15) * DQ + 8 * quad);
    floatx4 s0 = __builtin_amdgcn_mfma_f32_16x16x32_bf16(aq, kb0, z4, 0, 0, 0);
    floatx4 s1 = __builtin_amdgcn_mfma_f32_16x16x32_bf16(aq, kb1, z4, 0, 0, 0);

    const ushort_t* vb = vG + (size_t)m0 + 8 * quad;
    short8 av0 = *(const short8*)(vb + (size_t)(cw +  0 + l15) * N);
    short8 av1 = *(const short8*)(vb + (size_t)(cw + 16 + l15) * N);
    short8 av2 = *(const short8*)(vb + (size_t)(cw + 32 + l15) * N);
    short8 av3 = *(const short8*)(vb + (size_t)(cw + 48 + l15) * N);

    ushort_t* pb = &Pb[it & 1][0][0];
#pragma unroll
    for (int r = 0; r < 4; ++r) {
      float p0 = exp2f(s0[r]);
      float p1 = exp2f(s1[r]);
      lsum[r] += p0 + p1;
      const int row = 16 * w + 4 * quad + r;
      pb[row * 36 + l15]      = f2bf_fast(p0);
      pb[row * 36 + 16 + l15] = f2bf_fast(p1);
    }
    __syncthreads();

#pragma unroll
    for (int b2 = 0; b2 < 4; ++b2) {
      const ushort_t* pr = pb + (b2 * 16 + l15) * 36 + 8 * quad;
      union { uint2 u2[2]; short8 v; } u;
      u.u2[0] = *(const uint2*)(pr);
      u.u2[1] = *(const uint2*)(pr + 4);
      const short8 pf = u.v;
      acc[0][b2] = __builtin_amdgcn_mfma_f32_16x16x32_bf16(av0, pf, acc[0][b2], 0, 0, 0);
      acc[1][b2] = __builtin_amdgcn_mfma_f32_16x16x32_bf16(av1, pf, acc[1][b2], 0, 0, 0);
      acc[2][b2] = __builtin_amdgcn_mfma_f32_16x16x32_bf16(av2, pf, acc[2][b2], 0, 0, 0);
      acc[3][b2] = __builtin_amdgcn_mfma_f32_16x16x32_bf16(av3, pf, acc[3][b2], 0, 0, 0);
    }
  }

#pragma unroll
  for (int r = 0; r < 4; ++r) {
    float v = lsum[r];
    v += __shfl_xor(v, 1);
    v += __shfl_xor(v, 2);
    v += __shfl_xor(v, 4);
    v += __shfl_xor(v, 8);
    lsum[r] = v;
  }
  if (l15 == 0) {
#pragma unroll
    for (int r = 0; r < 4; ++r)
      lpart[(size_t)s * N + n0 + 16 * w + 4 * quad + r] = lsum[r];
  }

  const size_t basep = ((size_t)s * NT + nt) * 256;
#pragma unroll
  for (int a2 = 0; a2 < 4; ++a2)
#pragma unroll
    for (int b2 = 0; b2 < 4; ++b2)
#pragma unroll
      for (int r = 0; r < 4; ++r) {
        const int c  = cw + a2 * 16 + 4 * quad + r;
        const int nl = b2 * 16 + l15;
        Opart[(basep + c) * 64 + nl] = f2bf(acc[a2][b2][r]);
      }
}

// ---------------------------------------------------------------------------
// Kernel 3: fused combine + gate-exp.  UNCHANGED (control).
// ---------------------------------------------------------------------------
template<int NSL>
__global__ __launch_bounds__(1024) void cco_kernel(
    const ushort_t* __restrict__ Opart, const float* __restrict__ lpart,
    float* __restrict__ e_buf, float* __restrict__ sumExp)
{
  const int nt = blockIdx.x;
  const int t = threadIdx.x;
  const int n = t & 63, ci = t >> 6;   // ci in [0,16)
  float mx = -3.4e38f, sm = 0.f;
#pragma unroll
  for (int k = 0; k < 16; ++k) {
    const int c = ci * 16 + k;
    float val = 0.f;
#pragma unroll
    for (int s2 = 0; s2 < NSL; ++s2)
      val += bf2f(Opart[(((size_t)s2 * NT + nt) * 256 + c) * 64 + n]);
    mx = fmaxf(mx, val);
    sm += val;
  }
  __shared__ float rmx[16][64], rsm[16][64];
  rmx[ci][n] = mx; rsm[ci][n] = sm;
  __syncthreads();
  if (t < 64) {
    float m = rmx[0][t], s = rsm[0][t];
#pragma unroll
    for (int g = 1; g < 16; ++g) { m = fmaxf(m, rmx[g][t]); s += rsm[g][t]; }
    float l = 0.f;
#pragma unroll
    for (int s3 = 0; s3 < NSL; ++s3) l += lpart[(size_t)s3 * N + nt * 64 + t];
    const float oc = (m + s * (1.0f / 256.0f)) / l;
    const float ev = exp2f(oc * (0.0625f * LOG2E));
    e_buf[nt * 64 + t] = ev;
    float vs = ev;
    vs += __shfl_xor(vs, 1);  vs += __shfl_xor(vs, 2);
    vs += __shfl_xor(vs, 4);  vs += __shfl_xor(vs, 8);
    vs += __shfl_xor(vs, 16); vs += __shfl_xor(vs, 32);
    if (t == 0) atomicAdd(sumExp, vs);
  }
}

// ---------------------------------------------------------------------------
// Kernel 4: final 1x1 conv via bf16 MFMA + fp32 epilogue.
// out = x + (1+gamma)*(x_co[n]*(W6@x)[o][n] + b6[o]);  x_co = e_buf/sumExp.
// x addend and b6 stay fp32-exact; bf16 GEMM error is damped by x_co ~1e-4.
// grid (144 n-tiles, 4 o-chunks), 256 threads.
// ---------------------------------------------------------------------------
__global__ __launch_bounds__(256) void final_mfma(
    const float* __restrict__ x, const float* __restrict__ W6,
    const float* __restrict__ b6, const float* __restrict__ gamma,
    const float* __restrict__ e_buf, const float* __restrict__ sumExp,
    float* __restrict__ out)
{
  __shared__ ushort_t xbT[64][XBT_STRIDE];
  const int t = threadIdx.x;
  const int n0 = blockIdx.x * 64;
  const int w = t >> 6, lane = t & 63;
  const int quad = lane >> 4, l15 = lane & 15;

  stage_x_tile(x, n0, t, xbT);
  __syncthreads();

  const int obase = blockIdx.y * 64 + w * 16;
  const float* Arow = W6 + (size_t)(obase + l15) * CIN;

  floatx4 acc[4];
#pragma unroll
  for (int b2 = 0; b2 < 4; ++b2) acc[b2] = (floatx4){0.f, 0.f, 0.f, 0.f};

#pragma unroll
  for (int ks = 0; ks < 8; ++ks) {
    const short8 af = mk_bf16x8(Arow + ks * 32 + 8 * quad);
#pragma unroll
    for (int b2 = 0; b2 < 4; ++b2) {
      const short8 bf = *(const short8*)&xbT[b2 * 16 + l15][ks * 32 + 8 * quad];
      acc[b2] = __builtin_amdgcn_mfma_f32_16x16x32_bf16(af, bf, acc[b2], 0, 0, 0);
    }
  }

  const float g1 = 1.0f + gamma[0];
  const float inv = 1.0f / sumExp[0];
#pragma unroll
  for (int b2 = 0; b2 < 4; ++b2) {
    const int n = n0 + b2 * 16 + l15;
    const float xc = e_buf[n] * inv;
#pragma unroll
    for (int r = 0; r < 4; ++r) {
      const int o = obase + 4 * quad + r;
      const float xv = x[(size_t)o * N + n];
      out[(size_t)o * N + n] = xv + g1 * (xc * acc[b2][r] + b6[o]);
    }
  }
}

// ---------------------------------------------------------------------------
extern "C" void kernel_launch(void* const* d_in, const int* in_sizes, int n_in,
                              void* d_out, int out_size, void* d_ws, size_t ws_size,
                              hipStream_t stream)
{
  const float* x     = (const float*)d_in[0];
  const float* Wq    = (const float*)d_in[1];
  const float* bq    = (const float*)d_in[2];
  const float* Wk    = (const float*)d_in[3];
  const float* bk    = (const float*)d_in[4];
  const float* Wv    = (const float*)d_in[5];
  const float* bv    = (const float*)d_in[6];
  const float* W6    = (const float*)d_in[7];
  const float* b6    = (const float*)d_in[8];
  const float* gamma = (const float*)d_in[9];
  float* out = (float*)d_out;

  const size_t fixed = (size_t)N * DQ * 2 * 2        // qT,kT
                     + (size_t)CIN * N * 2            // vG
                     + (size_t)N * 4                  // e_buf
                     + 256;                           // sumExp (+pad)
  int nsl = 7;
  size_t need = fixed + (size_t)nsl * NT * 256 * 64 * 2 + (size_t)nsl * N * 4;
  if (ws_size < need) nsl = 4;
  const int totIters = N / 32;                        // 288
  const int base = totIters / nsl;
  const int rem  = totIters % nsl;

  char* ws = (char*)d_ws;
  const size_t OFF_QT = 0;
  const size_t OFF_KT = OFF_QT + (size_t)N * DQ * 2;
  const size_t OFF_V  = OFF_KT + (size_t)N * DQ * 2;
  const size_t OFF_OP = OFF_V  + (size_t)CIN * N * 2;
  const size_t OFF_LP = OFF_OP + (size_t)nsl * NT * 256 * 64 * 2;
  const size_t OFF_EB = OFF_LP + (size_t)nsl * N * 4;
  const size_t OFF_SE = OFF_EB + (size_t)N * 4;

  ushort_t* qT     = (ushort_t*)(ws + OFF_QT);
  ushort_t* kT     = (ushort_t*)(ws + OFF_KT);
  ushort_t* vG     = (ushort_t*)(ws + OFF_V);
  ushort_t* Opart  = (ushort_t*)(ws + OFF_OP);
  float*    lpart  = (float*)(ws + OFF_LP);
  float*    e_buf  = (float*)(ws + OFF_EB);
  float*    sumExp = (float*)(ws + OFF_SE);

  qkv_mfma<<<dim3(NT, 5), 256, 0, stream>>>(x, Wq, bq, Wk, bk, Wv, bv, qT, kT, vG, sumExp);
  attn_kernel<<<dim3(NT, nsl), 256, 0, stream>>>(qT, kT, vG, Opart, lpart, base, rem);
  if (nsl == 7) cco_kernel<7><<<NT, 1024, 0, stream>>>(Opart, lpart, e_buf, sumExp);
  else          cco_kernel<4><<<NT, 1024, 0, stream>>>(Opart, lpart, e_buf, sumExp);
  final_mfma<<<dim3(NT, 4), 256, 0, stream>>>(x, W6, b6, gamma, e_buf, sumExp, out);
}